// Round 14
// baseline (165.927 us; speedup 1.0000x reference)
//
#include <hip/hip_runtime.h>

// ---------------------------------------------------------------------------
// PairWiseCrossAttention: B=8, N=1024, D=768, H=12, HD=64
// convert(all->bf16) -> fused QKV+KV GEMM (256x256, 4-phase/tile, derived
// counted vmcnt) -> flash attn (kv-split, 1-tile pipelined PV) -> out GEMM
// ---------------------------------------------------------------------------

typedef __bf16 bf16x8 __attribute__((ext_vector_type(8)));
typedef float  f32x4  __attribute__((ext_vector_type(4)));
typedef unsigned int u32x4 __attribute__((ext_vector_type(4)));
typedef short  s16x4  __attribute__((ext_vector_type(4)));

__device__ __forceinline__ unsigned short bf16bits(float f) {
    return __builtin_bit_cast(unsigned short, (__bf16)f);
}
__device__ __forceinline__ unsigned pk2(float a, float b) {
    return (unsigned)bf16bits(a) | ((unsigned)bf16bits(b) << 16);
}
__device__ __forceinline__ bf16x8 asbf(u32x4 v) {
    return __builtin_bit_cast(bf16x8, v);
}
__device__ __forceinline__ float fexp2(float x) {
#if __has_builtin(__builtin_amdgcn_exp2f)
    return __builtin_amdgcn_exp2f(x);
#else
    return exp2f(x);
#endif
}
__device__ __forceinline__ float frcp(float x) {
#if __has_builtin(__builtin_amdgcn_rcpf)
    return __builtin_amdgcn_rcpf(x);
#else
    return 1.0f / x;
#endif
}

#define MFMA32(a, b, c) __builtin_amdgcn_mfma_f32_16x16x32_bf16((a), (b), (c), 0, 0, 0)
#define AS1(p) (const __attribute__((address_space(1))) void*)(p)
#define AS3(p) (__attribute__((address_space(3))) void*)(p)

// ---------------------------------------------------------------------------
// Convert everything to bf16 once.
// ---------------------------------------------------------------------------
__global__ __launch_bounds__(256) void convert_all(
    const float* __restrict__ x1, const float* __restrict__ x2,
    const float* __restrict__ Wq, const float* __restrict__ Wk,
    const float* __restrict__ Wv, const float* __restrict__ Wo,
    unsigned short* __restrict__ x1b, unsigned short* __restrict__ x2b,
    unsigned short* __restrict__ Wcat, unsigned short* __restrict__ Wob)
{
    const float* src; unsigned short* dst; int n4;
    switch (blockIdx.y) {
        case 0:  src = x1; dst = x1b;            n4 = 1572864; break;
        case 1:  src = x2; dst = x2b;            n4 = 1572864; break;
        case 2:  src = Wq; dst = Wcat;           n4 = 147456;  break;
        case 3:  src = Wk; dst = Wcat +  589824; n4 = 147456;  break;
        case 4:  src = Wv; dst = Wcat + 1179648; n4 = 147456;  break;
        default: src = Wo; dst = Wob;            n4 = 147456;  break;
    }
    int i = blockIdx.x * 256 + threadIdx.x;
    if (i >= n4) return;
    float4 v = ((const float4*)src)[i];
    unsigned* o32 = (unsigned*)(dst + (size_t)i * 4);
    o32[0] = pk2(v.x, v.y);
    o32[1] = pk2(v.z, v.w);
}

// ---------------------------------------------------------------------------
// 256x256 projection GEMM, 4 phases/K-tile, derived counted waits (R12).
// ---------------------------------------------------------------------------
__global__ __launch_bounds__(512, 2) void gemm256(
    const unsigned short* __restrict__ A1, const unsigned short* __restrict__ A2,
    const unsigned short* __restrict__ Wcat,
    unsigned short* __restrict__ dQ, unsigned short* __restrict__ dK,
    unsigned short* __restrict__ dV)
{
    __shared__ u32x4 smA[2][2048];   // [buf][256 rows x 8 granules] 32KB each
    __shared__ u32x4 smB[2][2048];

    const int tid  = threadIdx.x;
    const int lane = tid & 63;
    const int l15  = lane & 15;
    const int g    = lane >> 4;
    const int wid  = tid >> 6;       // 0..7
    const int wm   = wid >> 2;       // 0..1  (A half)
    const int wn   = wid & 3;        // 0..3  (B band)
    const int rb   = blockIdx.x;     // 0..31
    const int jb   = blockIdx.y;     // 0..14

    const bool br2 = (jb >= 9);
    const unsigned short* A  = br2 ? A2 : A1;
    const unsigned short* Bw = br2 ? (Wcat + 589824) : Wcat;
    const int jcol = br2 ? (jb - 9) : jb;

    f32x4 acc[8][4] = {};

#define STG_A(KT, BUF, MH, K)                                                        \
    {                                                                                \
        int s_  = wn * 64 + (K) * 256 + lane;                                        \
        int rl_ = s_ >> 3, ps_ = s_ & 7;                                             \
        const unsigned short* src_ = A +                                             \
            (size_t)(rb * 256 + wm * 128 + (MH) * 64 + rl_) * 768 +                  \
            (KT) * 64 + (ps_ ^ (rl_ & 7)) * 8;                                       \
        __builtin_amdgcn_global_load_lds(AS1(src_),                                  \
            AS3(&smA[BUF][wm * 1024 + (MH) * 512 + wn * 64 + (K) * 256]), 16, 0, 0); \
    }
#define STG_B(KT, BUF, K)                                                            \
    {                                                                                \
        int s_  = wm * 64 + (K) * 128 + lane;                                        \
        int rl_ = s_ >> 3, ps_ = s_ & 7;                                             \
        const unsigned short* src_ = Bw +                                            \
            (size_t)(jcol * 256 + wn * 64 + rl_) * 768 +                             \
            (KT) * 64 + (ps_ ^ (rl_ & 7)) * 8;                                       \
        __builtin_amdgcn_global_load_lds(AS1(src_),                                  \
            AS3(&smB[BUF][wn * 512 + wm * 64 + (K) * 128]), 16, 0, 0);               \
    }

    STG_A(0, 0, 0, 0) STG_A(0, 0, 0, 1)
    STG_B(0, 0, 0) STG_B(0, 0, 1) STG_B(0, 0, 2) STG_B(0, 0, 3)
    STG_A(0, 0, 1, 0) STG_A(0, 0, 1, 1)
    asm volatile("s_waitcnt vmcnt(0)" ::: "memory");
    __builtin_amdgcn_s_barrier();

    for (int kt = 0; kt < 12; ++kt) {
        const int buf = kt & 1;
        const int nb  = buf ^ 1;
        const bool st = (kt < 11);
        const u32x4* bA = smA[buf];
        const u32x4* bB = smB[buf];
        bf16x8 af[4], bfr[4];

        // ---------- q0: (mh0, kk0); stage A-mh0(kt+1)
#pragma unroll
        for (int n = 0; n < 4; ++n) {
            int row = wn * 64 + n * 16 + l15;
            bfr[n] = asbf(bB[row * 8 + (g ^ (row & 7))]);
        }
#pragma unroll
        for (int m = 0; m < 4; ++m) {
            int row = wm * 128 + m * 16 + l15;
            af[m] = asbf(bA[row * 8 + (g ^ (row & 7))]);
        }
        if (st) { STG_A(kt + 1, nb, 0, 0) STG_A(kt + 1, nb, 0, 1) }
        if (kt == 11) { asm volatile("s_waitcnt vmcnt(0)" ::: "memory"); }
        else          { asm volatile("s_waitcnt vmcnt(2)" ::: "memory"); }
        __builtin_amdgcn_sched_barrier(0);
        __builtin_amdgcn_s_barrier();
        __builtin_amdgcn_sched_barrier(0);
        __builtin_amdgcn_s_setprio(1);
#pragma unroll
        for (int m = 0; m < 4; ++m)
#pragma unroll
            for (int n = 0; n < 4; ++n)
                acc[m][n] = MFMA32(af[m], bfr[n], acc[m][n]);
        __builtin_amdgcn_s_setprio(0);

        // ---------- q1: (mh1, kk0); stage B(kt+1) parts 0,1
#pragma unroll
        for (int m = 0; m < 4; ++m) {
            int row = wm * 128 + 64 + m * 16 + l15;
            af[m] = asbf(bA[row * 8 + (g ^ (row & 7))]);
        }
        if (st) { STG_B(kt + 1, nb, 0) STG_B(kt + 1, nb, 1) }
        __builtin_amdgcn_sched_barrier(0);
        __builtin_amdgcn_s_barrier();
        __builtin_amdgcn_sched_barrier(0);
        __builtin_amdgcn_s_setprio(1);
#pragma unroll
        for (int m = 0; m < 4; ++m)
#pragma unroll
            for (int n = 0; n < 4; ++n)
                acc[4 + m][n] = MFMA32(af[m], bfr[n], acc[4 + m][n]);
        __builtin_amdgcn_s_setprio(0);

        // ---------- q2: (mh0, kk1); stage B(kt+1) parts 2,3
#pragma unroll
        for (int n = 0; n < 4; ++n) {
            int row = wn * 64 + n * 16 + l15;
            bfr[n] = asbf(bB[row * 8 + ((4 + g) ^ (row & 7))]);
        }
#pragma unroll
        for (int m = 0; m < 4; ++m) {
            int row = wm * 128 + m * 16 + l15;
            af[m] = asbf(bA[row * 8 + ((4 + g) ^ (row & 7))]);
        }
        if (st) { STG_B(kt + 1, nb, 2) STG_B(kt + 1, nb, 3) }
        __builtin_amdgcn_sched_barrier(0);
        __builtin_amdgcn_s_barrier();
        __builtin_amdgcn_sched_barrier(0);
        __builtin_amdgcn_s_setprio(1);
#pragma unroll
        for (int m = 0; m < 4; ++m)
#pragma unroll
            for (int n = 0; n < 4; ++n)
                acc[m][n] = MFMA32(af[m], bfr[n], acc[m][n]);
        __builtin_amdgcn_s_setprio(0);

        // ---------- q3: (mh1, kk1); stage A-mh1(kt+1); end-of-tile wait
#pragma unroll
        for (int m = 0; m < 4; ++m) {
            int row = wm * 128 + 64 + m * 16 + l15;
            af[m] = asbf(bA[row * 8 + ((4 + g) ^ (row & 7))]);
        }
        if (st) { STG_A(kt + 1, nb, 1, 0) STG_A(kt + 1, nb, 1, 1) }
        if (st) { asm volatile("s_waitcnt vmcnt(2)" ::: "memory"); }
        __builtin_amdgcn_sched_barrier(0);
        __builtin_amdgcn_s_barrier();
        __builtin_amdgcn_sched_barrier(0);
        __builtin_amdgcn_s_setprio(1);
#pragma unroll
        for (int m = 0; m < 4; ++m)
#pragma unroll
            for (int n = 0; n < 4; ++n)
                acc[4 + m][n] = MFMA32(af[m], bfr[n], acc[4 + m][n]);
        __builtin_amdgcn_s_setprio(0);
    }
#undef STG_A
#undef STG_B

    const int rloc = wm * 128 + g * 4;
    const int cloc = wn * 64 + l15;
    const int seg  = jcol / 3;
    const int segq = br2 ? seg + 3 : seg;          // 0=Q 1=K1 2=V1 3=K2 4=V2
    const int cseg = (jcol - seg * 3) * 256;
#pragma unroll
    for (int mf = 0; mf < 8; ++mf) {
#pragma unroll
        for (int n = 0; n < 4; ++n) {
            int r0 = rb * 256 + rloc + mf * 16;
            int cl = cseg + cloc + n * 16;
            int b = r0 >> 10, nn = r0 & 1023;
            int h = cl >> 6, hd = cl & 63;
            if (segq == 0) {
#pragma unroll
                for (int reg = 0; reg < 4; ++reg)
                    dQ[((size_t)(b * 12 + h) * 1024 + nn + reg) * 64 + hd] =
                        bf16bits(acc[mf][n][reg] * 0.18033688f);   // 0.125*log2(e)
            } else if (segq == 1 || segq == 3) {
                size_t koff = (segq == 3) ? 1024 : 0;
#pragma unroll
                for (int reg = 0; reg < 4; ++reg)
                    dK[((size_t)(b * 12 + h) * 2048 + koff + nn + reg) * 64 + hd] =
                        bf16bits(acc[mf][n][reg]);
            } else {
                size_t koff = (segq == 4) ? 1024 : 0;
                uint2 w;
                w.x = pk2(acc[mf][n][0], acc[mf][n][1]);
                w.y = pk2(acc[mf][n][2], acc[mf][n][3]);
                *(uint2*)(dV + ((size_t)(b * 12 + h) * 64 + hd) * 2048 +
                          koff + nn) = w;
            }
        }
    }
}

// ---------------------------------------------------------------------------
// 128x128 2-phase GEMM for the output projection: C = AO . Wo^T + bo (fp32).
// ---------------------------------------------------------------------------
__global__ __launch_bounds__(256) void gemm_out(
    const unsigned short* __restrict__ A, const unsigned short* __restrict__ Bw,
    float* __restrict__ dO, const float* __restrict__ bias)
{
    __shared__ u32x4 smA[2048];
    __shared__ u32x4 smB[2048];

    const int tid  = threadIdx.x;
    const int lane = tid & 63;
    const int l15  = lane & 15;
    const int g    = lane >> 4;
    const int wid  = tid >> 6;
    const int rb   = blockIdx.x;
    const int jb   = blockIdx.y;
    const int wr   = (wid >> 1) * 64;
    const int wc   = (wid & 1) * 64;

    f32x4 acc[4][4] = {};

#define GSTAGE(KT, BO)                                                               \
    {                                                                                \
        int kt_ = (KT);                                                              \
        _Pragma("unroll")                                                            \
        for (int c_ = 0; c_ < 4; ++c_) {                                             \
            int i_   = (wid + c_ * 4) * 64 + lane;                                   \
            int row_ = i_ >> 3;                                                      \
            int gs_  = (i_ & 7) ^ (row_ & 7);                                        \
            const unsigned short* sa = A +                                           \
                (size_t)(rb * 128 + row_) * 768 + kt_ * 64 + gs_ * 8;                \
            __builtin_amdgcn_global_load_lds(AS1(sa),                                \
                AS3(smA + (BO) + (wid + c_ * 4) * 64), 16, 0, 0);                    \
            const unsigned short* sb = Bw +                                          \
                (size_t)(jb * 128 + row_) * 768 + kt_ * 64 + gs_ * 8;                \
            __builtin_amdgcn_global_load_lds(AS1(sb),                                \
                AS3(smB + (BO) + (wid + c_ * 4) * 64), 16, 0, 0);                    \
        }                                                                            \
    }

    GSTAGE(0, 0)

    for (int kt = 0; kt < 12; ++kt) {
        __builtin_amdgcn_s_barrier();
        if (kt < 11) {
            GSTAGE(kt + 1, ((kt + 1) & 1) << 10)
            asm volatile("s_waitcnt vmcnt(8)" ::: "memory");
        } else {
            asm volatile("s_waitcnt vmcnt(0)" ::: "memory");
        }
        __builtin_amdgcn_s_barrier();
        __builtin_amdgcn_sched_barrier(0);

        const u32x4* bA = smA + ((kt & 1) << 10);
        const u32x4* bB = smB + ((kt & 1) << 10);

#pragma unroll
        for (int kk = 0; kk < 2; ++kk) {
            bf16x8 af[4], bfr[4];
#pragma unroll
            for (int m = 0; m < 4; ++m) {
                int row = wr + m * 16 + l15;
                af[m] = asbf(bA[row * 8 + ((kk * 4 + g) ^ (row & 7))]);
            }
#pragma unroll
            for (int n = 0; n < 4; ++n) {
                int row = wc + n * 16 + l15;
                bfr[n] = asbf(bB[row * 8 + ((kk * 4 + g) ^ (row & 7))]);
            }
#pragma unroll
            for (int m = 0; m < 4; ++m)
#pragma unroll
                for (int n = 0; n < 4; ++n)
                    acc[m][n] = MFMA32(af[m], bfr[n], acc[m][n]);
        }
    }
#undef GSTAGE

    const int rloc = wr + g * 4;
    const int cloc = wc + l15;
#pragma unroll
    for (int m = 0; m < 4; ++m)
#pragma unroll
        for (int n = 0; n < 4; ++n) {
            int r0 = rb * 128 + rloc + m * 16;
            int c  = jb * 128 + cloc + n * 16;
#pragma unroll
            for (int reg = 0; reg < 4; ++reg)
                dO[(size_t)(r0 + reg) * 768 + c] = acc[m][n][reg] + bias[c];
        }
}

// ---------------------------------------------------------------------------
// Flash attention, kv-split waves + 1-tile pipelined PV.
// Iteration t: QK(t) and PV(t-1) issue back-to-back on the MFMA pipe, then
// softmax(t) VALU overlaps the PV drain (sched_barrier pins the order).
// Staging: K two tiles ahead, V ONE tile ahead (V(t-1) is live at iter t).
// Buffer safety: sK[(t+2)%3] last read by QK(t-1) (iter t-1, pre-barrier);
// sV[(t+1)%3] last read by PV(t-2) (iter t-1, pre-barrier). Waits derived:
// vmcnt(4) generic (iter t-1's 4 DMAs in flight), vmcnt(2) at t=31,
// vmcnt(0)+barrier before the post-loop PV(31).
// ---------------------------------------------------------------------------
__global__ __launch_bounds__(256, 3) void attn_k(
    const unsigned short* __restrict__ Q, const unsigned short* __restrict__ K,
    const unsigned short* __restrict__ Vt, unsigned short* __restrict__ AO)
{
    __shared__ u32x4 sK[1536];              // 3 bufs x (64 rows x 8 granules)
    __shared__ u32x4 sV[1536];

    const int tid  = threadIdx.x;
    const int lane = tid & 63;
    const int g    = lane >> 4;
    const int l15  = lane & 15;
    const int wid  = tid >> 6;
    const int qh   = wid & 1;               // q half (64 q each)
    const int kvh  = wid >> 1;              // kv half (32 kv each)
    const int bh   = blockIdx.x;            // fastest -> XCD = bh % 8
    const int q0   = blockIdx.y * 128;

    const unsigned short* Qh = Q  + (size_t)bh * (1024 * 64);
    const unsigned short* Kh = K  + (size_t)bh * (2048 * 64);
    const unsigned short* Vh = Vt + (size_t)bh * (64 * 2048);

    bf16x8 qf[4][2];
#pragma unroll
    for (int m = 0; m < 4; ++m)
#pragma unroll
        for (int kk = 0; kk < 2; ++kk)
            qf[m][kk] = *(const bf16x8*)(Qh +
                (size_t)(q0 + qh * 64 + m * 16 + l15) * 64 + kk * 32 + g * 8);

    f32x4 o[4][4] = {};                     // [v hd-frag][m q-frag], kv-partial
    float lr[4] = {0.f, 0.f, 0.f, 0.f};
    bf16x8 pfp[4];                          // previous tile's packed P

#define STAGE_K(T, DOFF)                                                             \
    {                                                                                \
        int t_ = (T);                                                                \
        _Pragma("unroll")                                                            \
        for (int c_ = 0; c_ < 2; ++c_) {                                             \
            int i_   = (wid + c_ * 4) * 64 + lane;                                   \
            int row_ = i_ >> 3;                                                      \
            int gsK_ = (i_ & 7) ^ ((row_ & 3) | ((row_ >> 1) & 4));                  \
            const unsigned short* srcK_ = Kh + ((size_t)t_ * 64 + row_) * 64 + gsK_ * 8; \
            __builtin_amdgcn_global_load_lds(AS1(srcK_),                             \
                AS3(sK + (DOFF) + (wid + c_ * 4) * 64), 16, 0, 0);                   \
        }                                                                            \
    }
#define STAGE_V(T, DOFF)                                                             \
    {                                                                                \
        int t_ = (T);                                                                \
        _Pragma("unroll")                                                            \
        for (int c_ = 0; c_ < 2; ++c_) {                                             \
            int i_   = (wid + c_ * 4) * 64 + lane;                                   \
            int row_ = i_ >> 3;                                                      \
            int gsV_ = (i_ & 7) ^ (row_ & 7);                                        \
            const unsigned short* srcV_ = Vh + (size_t)row_ * 2048 + t_ * 64 + gsV_ * 8; \
            __builtin_amdgcn_global_load_lds(AS1(srcV_),                             \
                AS3(sV + (DOFF) + (wid + c_ * 4) * 64), 16, 0, 0);                   \
        }                                                                            \
    }

    STAGE_K(0, 0)
    STAGE_V(0, 0)
    STAGE_K(1, 512)

    for (int t = 0; t < 32; ++t) {
        if (t < 31) { asm volatile("s_waitcnt vmcnt(4)" ::: "memory"); }
        else        { asm volatile("s_waitcnt vmcnt(2)" ::: "memory"); }
        __builtin_amdgcn_s_barrier();
        if (t < 30) STAGE_K(t + 2, ((t + 2) % 3) * 512)
        if (t < 31) STAGE_V(t + 1, ((t + 1) % 3) * 512)
        __builtin_amdgcn_sched_barrier(0);

        const u32x4* sKb = sK + (t % 3) * 512;

        // QK(t): 16 MFMA, then PV(t-1): 16 MFMA — back-to-back on matrix pipe
        f32x4 s[2][4] = {};
        __builtin_amdgcn_s_setprio(1);
#pragma unroll
        for (int kk = 0; kk < 2; ++kk) {
            bf16x8 kf[2];
#pragma unroll
            for (int j = 0; j < 2; ++j) {
                int rowp = (kvh << 5) + ((l15 >> 2) << 3) + (j << 2) + (l15 & 3);
                kf[j] = asbf(sKb[rowp * 8 + ((kk * 4 + g) ^ (l15 & 7))]);
            }
#pragma unroll
            for (int j = 0; j < 2; ++j)
#pragma unroll
                for (int m = 0; m < 4; ++m)
                    s[j][m] = MFMA32(kf[j], qf[m][kk], s[j][m]);
        }
        if (t > 0) {
            const u32x4* sVbp = sV + ((t + 2) % 3) * 512;   // (t-1)%3
#pragma unroll
            for (int v = 0; v < 4; ++v) {
                int row = v * 16 + l15;
                bf16x8 vf = asbf(sVbp[row * 8 + ((kvh * 4 + g) ^ (row & 7))]);
#pragma unroll
                for (int m = 0; m < 4; ++m)
                    o[v][m] = MFMA32(vf, pfp[m], o[v][m]);
            }
        }
        __builtin_amdgcn_s_setprio(0);
        __builtin_amdgcn_sched_barrier(0);   // pin PV issue before softmax VALU

        // softmax(t): p = 2^s -> pfp (overlaps PV(t-1) MFMA drain)
#pragma unroll
        for (int m = 0; m < 4; ++m) {
            float p0 = fexp2(s[0][m][0]), p1 = fexp2(s[0][m][1]);
            float p2 = fexp2(s[0][m][2]), p3 = fexp2(s[0][m][3]);
            float p4 = fexp2(s[1][m][0]), p5 = fexp2(s[1][m][1]);
            float p6 = fexp2(s[1][m][2]), p7 = fexp2(s[1][m][3]);
            lr[m] += (p0 + p1) + (p2 + p3) + (p4 + p5) + (p6 + p7);
            s16x4 a = (s16x4){ (short)bf16bits(p0), (short)bf16bits(p1),
                               (short)bf16bits(p2), (short)bf16bits(p3) };
            s16x4 b = (s16x4){ (short)bf16bits(p4), (short)bf16bits(p5),
                               (short)bf16bits(p6), (short)bf16bits(p7) };
            pfp[m] = __builtin_bit_cast(bf16x8,
                __builtin_shufflevector(a, b, 0, 1, 2, 3, 4, 5, 6, 7));
        }
    }

    // post-loop: PV(31)
    asm volatile("s_waitcnt vmcnt(0)" ::: "memory");
    __builtin_amdgcn_s_barrier();
    {
        const u32x4* sVbp = sV + (31 % 3) * 512;
        __builtin_amdgcn_s_setprio(1);
#pragma unroll
        for (int v = 0; v < 4; ++v) {
            int row = v * 16 + l15;
            bf16x8 vf = asbf(sVbp[row * 8 + ((kvh * 4 + g) ^ (row & 7))]);
#pragma unroll
            for (int m = 0; m < 4; ++m)
                o[v][m] = MFMA32(vf, pfp[m], o[v][m]);
        }
        __builtin_amdgcn_s_setprio(0);
    }

    // combine kv-halves through the (now dead) staging LDS
#pragma unroll
    for (int m = 0; m < 4; ++m) {
        lr[m] += __shfl_xor(lr[m], 16);
        lr[m] += __shfl_xor(lr[m], 32);
    }
    __syncthreads();

    float* oK   = (float*)sK;
    float* oVf  = (float*)sV;
    float* obuf = qh ? oVf : oK;
    float* lbuf = oVf + 64 * 72;

    if (kvh == 1) {
#pragma unroll
        for (int m = 0; m < 4; ++m)
#pragma unroll
            for (int v = 0; v < 4; ++v)
                *(f32x4*)&obuf[(m * 16 + l15) * 72 + v * 16 + g * 4] = o[v][m];
        if (lane < 16) {
#pragma unroll
            for (int m = 0; m < 4; ++m)
                lbuf[qh * 64 + m * 16 + l15] = lr[m];
        }
    }
    __syncthreads();

    if (kvh == 0) {
        const int b = bh / 12, h = bh % 12;
#pragma unroll
        for (int m = 0; m < 4; ++m) {
            float lt = lr[m] + lbuf[qh * 64 + m * 16 + l15];
            float rl = frcp(lt);
            int q = q0 + qh * 64 + m * 16 + l15;
            unsigned short* dst = AO + (size_t)(b * 1024 + q) * 768 + h * 64 + g * 4;
#pragma unroll
            for (int v = 0; v < 4; ++v) {
                f32x4 add = *(const f32x4*)&obuf[(m * 16 + l15) * 72 + v * 16 + g * 4];
                uint2 w;
                w.x = pk2((o[v][m][0] + add[0]) * rl, (o[v][m][1] + add[1]) * rl);
                w.y = pk2((o[v][m][2] + add[2]) * rl, (o[v][m][3] + add[3]) * rl);
                *(uint2*)(dst + v * 16) = w;
            }
        }
    }
#undef STAGE_K
#undef STAGE_V
}

// ---------------------------------------------------------------------------
extern "C" void kernel_launch(void* const* d_in, const int* in_sizes, int n_in,
                              void* d_out, int out_size, void* d_ws, size_t ws_size,
                              hipStream_t stream)
{
    const float* x1 = (const float*)d_in[0];
    const float* x2 = (const float*)d_in[1];
    const float* Wq = (const float*)d_in[2];
    const float* Wk = (const float*)d_in[3];
    const float* Wv = (const float*)d_in[4];
    const float* Wo = (const float*)d_in[5];
    const float* bo = (const float*)d_in[6];

    unsigned short* Wcat = (unsigned short*)d_ws;        // 2304x768
    unsigned short* Wob  = Wcat + 1769472;               // 768x768
    unsigned short* x1b  = Wob  + 589824;                // 8192x768
    unsigned short* x2b  = x1b  + 6291456;               // 8192x768
    unsigned short* Qb   = x2b  + 6291456;               // (B,H,1024,64)
    unsigned short* Kc   = Qb   + 6291456;               // (B,H,2048,64)
    unsigned short* Vt   = Kc   + 12582912;              // (B,H,64,2048)
    unsigned short* AO   = x1b;                          // alias (x1b dead)

    convert_all<<<dim3(6144, 6), 256, 0, stream>>>(x1, x2, Wq, Wk, Wv, Wo,
                                                   x1b, x2b, Wcat, Wob);

    gemm256<<<dim3(32, 15), 512, 0, stream>>>(x1b, x2b, Wcat, Qb, Kc, Vt);

    attn_k<<<dim3(96, 8), 256, 0, stream>>>(Qb, Kc, Vt, AO);

    gemm_out<<<dim3(64, 6), 256, 0, stream>>>(AO, Wob, (float*)d_out, bo);
}

// Round 15
// 146.094 us; speedup vs baseline: 1.1358x; 1.1358x over previous
//
#include <hip/hip_runtime.h>

// ---------------------------------------------------------------------------
// PairWiseCrossAttention: B=8, N=1024, D=768, H=12, HD=64
// convert(all->bf16, exact grid) -> fused QKV+KV GEMM (256x256, 4-phase/tile,
// derived counted vmcnt) -> flash attn (kv-split waves) -> out GEMM
// (R12 configuration — best measured — with convert grid trimmed)
// ---------------------------------------------------------------------------

typedef __bf16 bf16x8 __attribute__((ext_vector_type(8)));
typedef float  f32x4  __attribute__((ext_vector_type(4)));
typedef unsigned int u32x4 __attribute__((ext_vector_type(4)));
typedef short  s16x4  __attribute__((ext_vector_type(4)));

__device__ __forceinline__ unsigned short bf16bits(float f) {
    return __builtin_bit_cast(unsigned short, (__bf16)f);
}
__device__ __forceinline__ unsigned pk2(float a, float b) {
    return (unsigned)bf16bits(a) | ((unsigned)bf16bits(b) << 16);
}
__device__ __forceinline__ bf16x8 asbf(u32x4 v) {
    return __builtin_bit_cast(bf16x8, v);
}
__device__ __forceinline__ float fexp2(float x) {
#if __has_builtin(__builtin_amdgcn_exp2f)
    return __builtin_amdgcn_exp2f(x);
#else
    return exp2f(x);
#endif
}
__device__ __forceinline__ float frcp(float x) {
#if __has_builtin(__builtin_amdgcn_rcpf)
    return __builtin_amdgcn_rcpf(x);
#else
    return 1.0f / x;
#endif
}

#define MFMA32(a, b, c) __builtin_amdgcn_mfma_f32_16x16x32_bf16((a), (b), (c), 0, 0, 0)
#define AS1(p) (const __attribute__((address_space(1))) void*)(p)
#define AS3(p) (__attribute__((address_space(3))) void*)(p)

// ---------------------------------------------------------------------------
// Convert everything to bf16 once. Flat 1D grid, no empty blocks:
//   [0, 6144)        -> x1   (1,572,864 float4)
//   [6144, 12288)    -> x2
//   [12288, 14592)   -> weights: 4 segments x 576 blocks (147,456 float4 each)
// ---------------------------------------------------------------------------
__global__ __launch_bounds__(256) void convert_all(
    const float* __restrict__ x1, const float* __restrict__ x2,
    const float* __restrict__ Wq, const float* __restrict__ Wk,
    const float* __restrict__ Wv, const float* __restrict__ Wo,
    unsigned short* __restrict__ x1b, unsigned short* __restrict__ x2b,
    unsigned short* __restrict__ Wcat, unsigned short* __restrict__ Wob)
{
    int t = blockIdx.x;
    const float* src; unsigned short* dst; int i;
    if (t < 6144) {
        src = x1; dst = x1b; i = t * 256 + threadIdx.x;
    } else if (t < 12288) {
        src = x2; dst = x2b; i = (t - 6144) * 256 + threadIdx.x;
    } else {
        int w = t - 12288;
        int seg = w / 576, blk = w - seg * 576;
        switch (seg) {
            case 0:  src = Wq; dst = Wcat;           break;
            case 1:  src = Wk; dst = Wcat +  589824; break;
            case 2:  src = Wv; dst = Wcat + 1179648; break;
            default: src = Wo; dst = Wob;            break;
        }
        i = blk * 256 + threadIdx.x;
    }
    float4 v = ((const float4*)src)[i];
    unsigned* o32 = (unsigned*)(dst + (size_t)i * 4);
    o32[0] = pk2(v.x, v.y);
    o32[1] = pk2(v.z, v.w);
}

// ---------------------------------------------------------------------------
// 256x256 projection GEMM, 4 phases/K-tile, derived counted waits (R12).
// BK=64, 12 K-tiles, 8 waves (wm 0..1 x wn 0..3), 2 LDS buffers (128 KB).
// Stage plan during tile t (for t+1, 2 loads/phase):
//   q0: A-mh0  q1,q2: B  q3: A-mh1; waits vmcnt(2) at end-q0 / end-q3.
// jb<9: A=x1b -> segq 0=Q(*0.125*log2e) 1=K1 2=V1t ; jb>=9: A=x2b -> 3=K2 4=V2t
// ---------------------------------------------------------------------------
__global__ __launch_bounds__(512, 2) void gemm256(
    const unsigned short* __restrict__ A1, const unsigned short* __restrict__ A2,
    const unsigned short* __restrict__ Wcat,
    unsigned short* __restrict__ dQ, unsigned short* __restrict__ dK,
    unsigned short* __restrict__ dV)
{
    __shared__ u32x4 smA[2][2048];   // [buf][256 rows x 8 granules] 32KB each
    __shared__ u32x4 smB[2][2048];

    const int tid  = threadIdx.x;
    const int lane = tid & 63;
    const int l15  = lane & 15;
    const int g    = lane >> 4;
    const int wid  = tid >> 6;       // 0..7
    const int wm   = wid >> 2;       // 0..1  (A half)
    const int wn   = wid & 3;        // 0..3  (B band)
    const int rb   = blockIdx.x;     // 0..31
    const int jb   = blockIdx.y;     // 0..14

    const bool br2 = (jb >= 9);
    const unsigned short* A  = br2 ? A2 : A1;
    const unsigned short* Bw = br2 ? (Wcat + 589824) : Wcat;
    const int jcol = br2 ? (jb - 9) : jb;

    f32x4 acc[8][4] = {};

#define STG_A(KT, BUF, MH, K)                                                        \
    {                                                                                \
        int s_  = wn * 64 + (K) * 256 + lane;                                        \
        int rl_ = s_ >> 3, ps_ = s_ & 7;                                             \
        const unsigned short* src_ = A +                                             \
            (size_t)(rb * 256 + wm * 128 + (MH) * 64 + rl_) * 768 +                  \
            (KT) * 64 + (ps_ ^ (rl_ & 7)) * 8;                                       \
        __builtin_amdgcn_global_load_lds(AS1(src_),                                  \
            AS3(&smA[BUF][wm * 1024 + (MH) * 512 + wn * 64 + (K) * 256]), 16, 0, 0); \
    }
#define STG_B(KT, BUF, K)                                                            \
    {                                                                                \
        int s_  = wm * 64 + (K) * 128 + lane;                                        \
        int rl_ = s_ >> 3, ps_ = s_ & 7;                                             \
        const unsigned short* src_ = Bw +                                            \
            (size_t)(jcol * 256 + wn * 64 + rl_) * 768 +                             \
            (KT) * 64 + (ps_ ^ (rl_ & 7)) * 8;                                       \
        __builtin_amdgcn_global_load_lds(AS1(src_),                                  \
            AS3(&smB[BUF][wn * 512 + wm * 64 + (K) * 128]), 16, 0, 0);               \
    }

    STG_A(0, 0, 0, 0) STG_A(0, 0, 0, 1)
    STG_B(0, 0, 0) STG_B(0, 0, 1) STG_B(0, 0, 2) STG_B(0, 0, 3)
    STG_A(0, 0, 1, 0) STG_A(0, 0, 1, 1)
    asm volatile("s_waitcnt vmcnt(0)" ::: "memory");
    __builtin_amdgcn_s_barrier();

    for (int kt = 0; kt < 12; ++kt) {
        const int buf = kt & 1;
        const int nb  = buf ^ 1;
        const bool st = (kt < 11);
        const u32x4* bA = smA[buf];
        const u32x4* bB = smB[buf];
        bf16x8 af[4], bfr[4];

        // ---------- q0: (mh0, kk0); stage A-mh0(kt+1)
#pragma unroll
        for (int n = 0; n < 4; ++n) {
            int row = wn * 64 + n * 16 + l15;
            bfr[n] = asbf(bB[row * 8 + (g ^ (row & 7))]);
        }
#pragma unroll
        for (int m = 0; m < 4; ++m) {
            int row = wm * 128 + m * 16 + l15;
            af[m] = asbf(bA[row * 8 + (g ^ (row & 7))]);
        }
        if (st) { STG_A(kt + 1, nb, 0, 0) STG_A(kt + 1, nb, 0, 1) }
        if (kt == 11) { asm volatile("s_waitcnt vmcnt(0)" ::: "memory"); }
        else          { asm volatile("s_waitcnt vmcnt(2)" ::: "memory"); }
        __builtin_amdgcn_sched_barrier(0);
        __builtin_amdgcn_s_barrier();
        __builtin_amdgcn_sched_barrier(0);
        __builtin_amdgcn_s_setprio(1);
#pragma unroll
        for (int m = 0; m < 4; ++m)
#pragma unroll
            for (int n = 0; n < 4; ++n)
                acc[m][n] = MFMA32(af[m], bfr[n], acc[m][n]);
        __builtin_amdgcn_s_setprio(0);

        // ---------- q1: (mh1, kk0); stage B(kt+1) parts 0,1
#pragma unroll
        for (int m = 0; m < 4; ++m) {
            int row = wm * 128 + 64 + m * 16 + l15;
            af[m] = asbf(bA[row * 8 + (g ^ (row & 7))]);
        }
        if (st) { STG_B(kt + 1, nb, 0) STG_B(kt + 1, nb, 1) }
        __builtin_amdgcn_sched_barrier(0);
        __builtin_amdgcn_s_barrier();
        __builtin_amdgcn_sched_barrier(0);
        __builtin_amdgcn_s_setprio(1);
#pragma unroll
        for (int m = 0; m < 4; ++m)
#pragma unroll
            for (int n = 0; n < 4; ++n)
                acc[4 + m][n] = MFMA32(af[m], bfr[n], acc[4 + m][n]);
        __builtin_amdgcn_s_setprio(0);

        // ---------- q2: (mh0, kk1); stage B(kt+1) parts 2,3
#pragma unroll
        for (int n = 0; n < 4; ++n) {
            int row = wn * 64 + n * 16 + l15;
            bfr[n] = asbf(bB[row * 8 + ((4 + g) ^ (row & 7))]);
        }
#pragma unroll
        for (int m = 0; m < 4; ++m) {
            int row = wm * 128 + m * 16 + l15;
            af[m] = asbf(bA[row * 8 + ((4 + g) ^ (row & 7))]);
        }
        if (st) { STG_B(kt + 1, nb, 2) STG_B(kt + 1, nb, 3) }
        __builtin_amdgcn_sched_barrier(0);
        __builtin_amdgcn_s_barrier();
        __builtin_amdgcn_sched_barrier(0);
        __builtin_amdgcn_s_setprio(1);
#pragma unroll
        for (int m = 0; m < 4; ++m)
#pragma unroll
            for (int n = 0; n < 4; ++n)
                acc[m][n] = MFMA32(af[m], bfr[n], acc[m][n]);
        __builtin_amdgcn_s_setprio(0);

        // ---------- q3: (mh1, kk1); stage A-mh1(kt+1); end-of-tile wait
#pragma unroll
        for (int m = 0; m < 4; ++m) {
            int row = wm * 128 + 64 + m * 16 + l15;
            af[m] = asbf(bA[row * 8 + ((4 + g) ^ (row & 7))]);
        }
        if (st) { STG_A(kt + 1, nb, 1, 0) STG_A(kt + 1, nb, 1, 1) }
        if (st) { asm volatile("s_waitcnt vmcnt(2)" ::: "memory"); }
        __builtin_amdgcn_sched_barrier(0);
        __builtin_amdgcn_s_barrier();
        __builtin_amdgcn_sched_barrier(0);
        __builtin_amdgcn_s_setprio(1);
#pragma unroll
        for (int m = 0; m < 4; ++m)
#pragma unroll
            for (int n = 0; n < 4; ++n)
                acc[4 + m][n] = MFMA32(af[m], bfr[n], acc[4 + m][n]);
        __builtin_amdgcn_s_setprio(0);
    }
#undef STG_A
#undef STG_B

    const int rloc = wm * 128 + g * 4;
    const int cloc = wn * 64 + l15;
    const int seg  = jcol / 3;
    const int segq = br2 ? seg + 3 : seg;          // 0=Q 1=K1 2=V1 3=K2 4=V2
    const int cseg = (jcol - seg * 3) * 256;
#pragma unroll
    for (int mf = 0; mf < 8; ++mf) {
#pragma unroll
        for (int n = 0; n < 4; ++n) {
            int r0 = rb * 256 + rloc + mf * 16;
            int cl = cseg + cloc + n * 16;
            int b = r0 >> 10, nn = r0 & 1023;
            int h = cl >> 6, hd = cl & 63;
            if (segq == 0) {
#pragma unroll
                for (int reg = 0; reg < 4; ++reg)
                    dQ[((size_t)(b * 12 + h) * 1024 + nn + reg) * 64 + hd] =
                        bf16bits(acc[mf][n][reg] * 0.18033688f);   // 0.125*log2(e)
            } else if (segq == 1 || segq == 3) {
                size_t koff = (segq == 3) ? 1024 : 0;
#pragma unroll
                for (int reg = 0; reg < 4; ++reg)
                    dK[((size_t)(b * 12 + h) * 2048 + koff + nn + reg) * 64 + hd] =
                        bf16bits(acc[mf][n][reg]);
            } else {
                size_t koff = (segq == 4) ? 1024 : 0;
                uint2 w;
                w.x = pk2(acc[mf][n][0], acc[mf][n][1]);
                w.y = pk2(acc[mf][n][2], acc[mf][n][3]);
                *(uint2*)(dV + ((size_t)(b * 12 + h) * 64 + hd) * 2048 +
                          koff + nn) = w;
            }
        }
    }
}

// ---------------------------------------------------------------------------
// 128x128 2-phase GEMM for the output projection: C = AO . Wo^T + bo (fp32).
// ---------------------------------------------------------------------------
__global__ __launch_bounds__(256) void gemm_out(
    const unsigned short* __restrict__ A, const unsigned short* __restrict__ Bw,
    float* __restrict__ dO, const float* __restrict__ bias)
{
    __shared__ u32x4 smA[2048];
    __shared__ u32x4 smB[2048];

    const int tid  = threadIdx.x;
    const int lane = tid & 63;
    const int l15  = lane & 15;
    const int g    = lane >> 4;
    const int wid  = tid >> 6;
    const int rb   = blockIdx.x;
    const int jb   = blockIdx.y;
    const int wr   = (wid >> 1) * 64;
    const int wc   = (wid & 1) * 64;

    f32x4 acc[4][4] = {};

#define GSTAGE(KT, BO)                                                               \
    {                                                                                \
        int kt_ = (KT);                                                              \
        _Pragma("unroll")                                                            \
        for (int c_ = 0; c_ < 4; ++c_) {                                             \
            int i_   = (wid + c_ * 4) * 64 + lane;                                   \
            int row_ = i_ >> 3;                                                      \
            int gs_  = (i_ & 7) ^ (row_ & 7);                                        \
            const unsigned short* sa = A +                                           \
                (size_t)(rb * 128 + row_) * 768 + kt_ * 64 + gs_ * 8;                \
            __builtin_amdgcn_global_load_lds(AS1(sa),                                \
                AS3(smA + (BO) + (wid + c_ * 4) * 64), 16, 0, 0);                    \
            const unsigned short* sb = Bw +                                          \
                (size_t)(jb * 128 + row_) * 768 + kt_ * 64 + gs_ * 8;                \
            __builtin_amdgcn_global_load_lds(AS1(sb),                                \
                AS3(smB + (BO) + (wid + c_ * 4) * 64), 16, 0, 0);                    \
        }                                                                            \
    }

    GSTAGE(0, 0)

    for (int kt = 0; kt < 12; ++kt) {
        __builtin_amdgcn_s_barrier();
        if (kt < 11) {
            GSTAGE(kt + 1, ((kt + 1) & 1) << 10)
            asm volatile("s_waitcnt vmcnt(8)" ::: "memory");
        } else {
            asm volatile("s_waitcnt vmcnt(0)" ::: "memory");
        }
        __builtin_amdgcn_s_barrier();
        __builtin_amdgcn_sched_barrier(0);

        const u32x4* bA = smA + ((kt & 1) << 10);
        const u32x4* bB = smB + ((kt & 1) << 10);

#pragma unroll
        for (int kk = 0; kk < 2; ++kk) {
            bf16x8 af[4], bfr[4];
#pragma unroll
            for (int m = 0; m < 4; ++m) {
                int row = wr + m * 16 + l15;
                af[m] = asbf(bA[row * 8 + ((kk * 4 + g) ^ (row & 7))]);
            }
#pragma unroll
            for (int n = 0; n < 4; ++n) {
                int row = wc + n * 16 + l15;
                bfr[n] = asbf(bB[row * 8 + ((kk * 4 + g) ^ (row & 7))]);
            }
#pragma unroll
            for (int m = 0; m < 4; ++m)
#pragma unroll
                for (int n = 0; n < 4; ++n)
                    acc[m][n] = MFMA32(af[m], bfr[n], acc[m][n]);
        }
    }
#undef GSTAGE

    const int rloc = wr + g * 4;
    const int cloc = wc + l15;
#pragma unroll
    for (int m = 0; m < 4; ++m)
#pragma unroll
        for (int n = 0; n < 4; ++n) {
            int r0 = rb * 128 + rloc + m * 16;
            int c  = jb * 128 + cloc + n * 16;
#pragma unroll
            for (int reg = 0; reg < 4; ++reg)
                dO[(size_t)(r0 + reg) * 768 + c] = acc[m][n][reg] + bias[c];
        }
}

// ---------------------------------------------------------------------------
// Flash attention (R12 exact — best measured). kv-split waves:
// wave (qh,kvh) computes q-half qh (64 q) x kv-half kvh (32 kv); half the
// LDS reads of the duplicated form. Fixed-max softmax (p = 2^s, order-free)
// -> O,l additive over kv, combined once at the end via the dead staging LDS.
// ---------------------------------------------------------------------------
__global__ __launch_bounds__(256, 3) void attn_k(
    const unsigned short* __restrict__ Q, const unsigned short* __restrict__ K,
    const unsigned short* __restrict__ Vt, unsigned short* __restrict__ AO)
{
    __shared__ u32x4 sK[1536];              // 3 bufs x (64 rows x 8 granules)
    __shared__ u32x4 sV[1536];

    const int tid  = threadIdx.x;
    const int lane = tid & 63;
    const int g    = lane >> 4;
    const int l15  = lane & 15;
    const int wid  = tid >> 6;
    const int qh   = wid & 1;               // q half (64 q each)
    const int kvh  = wid >> 1;              // kv half (32 kv each)
    const int bh   = blockIdx.x;            // fastest -> XCD = bh % 8
    const int q0   = blockIdx.y * 128;

    const unsigned short* Qh = Q  + (size_t)bh * (1024 * 64);
    const unsigned short* Kh = K  + (size_t)bh * (2048 * 64);
    const unsigned short* Vh = Vt + (size_t)bh * (64 * 2048);

    bf16x8 qf[4][2];
#pragma unroll
    for (int m = 0; m < 4; ++m)
#pragma unroll
        for (int kk = 0; kk < 2; ++kk)
            qf[m][kk] = *(const bf16x8*)(Qh +
                (size_t)(q0 + qh * 64 + m * 16 + l15) * 64 + kk * 32 + g * 8);

    f32x4 o[4][4] = {};                     // [v hd-frag][m q-frag], kv-partial
    float lr[4] = {0.f, 0.f, 0.f, 0.f};

#define STAGE_TILE(T, DOFF)                                                          \
    {                                                                                \
        int t_ = (T);                                                                \
        _Pragma("unroll")                                                            \
        for (int c_ = 0; c_ < 2; ++c_) {                                             \
            int i_   = (wid + c_ * 4) * 64 + lane;                                   \
            int row_ = i_ >> 3;                                                      \
            int gsK_ = (i_ & 7) ^ ((row_ & 3) | ((row_ >> 1) & 4));                  \
            int gsV_ = (i_ & 7) ^ (row_ & 7);                                        \
            const unsigned short* srcK_ = Kh + ((size_t)t_ * 64 + row_) * 64 + gsK_ * 8; \
            __builtin_amdgcn_global_load_lds(AS1(srcK_),                             \
                AS3(sK + (DOFF) + (wid + c_ * 4) * 64), 16, 0, 0);                   \
            const unsigned short* srcV_ = Vh + (size_t)row_ * 2048 + t_ * 64 + gsV_ * 8; \
            __builtin_amdgcn_global_load_lds(AS1(srcV_),                             \
                AS3(sV + (DOFF) + (wid + c_ * 4) * 64), 16, 0, 0);                   \
        }                                                                            \
    }

    STAGE_TILE(0, 0)
    STAGE_TILE(1, 512)

    for (int t = 0; t < 32; ++t) {
        if (t < 31) { asm volatile("s_waitcnt vmcnt(4)" ::: "memory"); }
        else        { asm volatile("s_waitcnt vmcnt(0)" ::: "memory"); }
        __builtin_amdgcn_s_barrier();
        if (t < 30) {
            STAGE_TILE(t + 2, ((t + 2) % 3) * 512)
        }
        __builtin_amdgcn_sched_barrier(0);

        const u32x4* sKb = sK + (t % 3) * 512;
        const u32x4* sVb = sV + (t % 3) * 512;

        f32x4 s[2][4] = {};
        __builtin_amdgcn_s_setprio(1);
#pragma unroll
        for (int kk = 0; kk < 2; ++kk) {
            bf16x8 kf[2];
#pragma unroll
            for (int j = 0; j < 2; ++j) {
                int rowp = (kvh << 5) + ((l15 >> 2) << 3) + (j << 2) + (l15 & 3);
                kf[j] = asbf(sKb[rowp * 8 + ((kk * 4 + g) ^ (l15 & 7))]);
            }
#pragma unroll
            for (int j = 0; j < 2; ++j)
#pragma unroll
                for (int m = 0; m < 4; ++m)
                    s[j][m] = MFMA32(kf[j], qf[m][kk], s[j][m]);
        }
        __builtin_amdgcn_s_setprio(0);

        s16x4 p16[2][4];
#pragma unroll
        for (int m = 0; m < 4; ++m) {
            float p0 = fexp2(s[0][m][0]), p1 = fexp2(s[0][m][1]);
            float p2 = fexp2(s[0][m][2]), p3 = fexp2(s[0][m][3]);
            float p4 = fexp2(s[1][m][0]), p5 = fexp2(s[1][m][1]);
            float p6 = fexp2(s[1][m][2]), p7 = fexp2(s[1][m][3]);
            lr[m] += (p0 + p1) + (p2 + p3) + (p4 + p5) + (p6 + p7);
            p16[0][m] = (s16x4){ (short)bf16bits(p0), (short)bf16bits(p1),
                                 (short)bf16bits(p2), (short)bf16bits(p3) };
            p16[1][m] = (s16x4){ (short)bf16bits(p4), (short)bf16bits(p5),
                                 (short)bf16bits(p6), (short)bf16bits(p7) };
        }

        __builtin_amdgcn_s_setprio(1);
        bf16x8 pf[4];
#pragma unroll
        for (int m = 0; m < 4; ++m)
            pf[m] = __builtin_bit_cast(bf16x8,
                __builtin_shufflevector(p16[0][m], p16[1][m],
                                        0, 1, 2, 3, 4, 5, 6, 7));
#pragma unroll
        for (int v = 0; v < 4; ++v) {
            int row = v * 16 + l15;
            bf16x8 vf = asbf(sVb[row * 8 + ((kvh * 4 + g) ^ (row & 7))]);
#pragma unroll
            for (int m = 0; m < 4; ++m)
                o[v][m] = MFMA32(vf, pf[m], o[v][m]);
        }
        __builtin_amdgcn_s_setprio(0);
    }

    // combine kv-halves through the (now dead) staging LDS
#pragma unroll
    for (int m = 0; m < 4; ++m) {
        lr[m] += __shfl_xor(lr[m], 16);
        lr[m] += __shfl_xor(lr[m], 32);
    }
    __syncthreads();

    float* oK   = (float*)sK;
    float* oVf  = (float*)sV;
    float* obuf = qh ? oVf : oK;
    float* lbuf = oVf + 64 * 72;

    if (kvh == 1) {
#pragma unroll
        for (int m = 0; m < 4; ++m)
#pragma unroll
            for (int v = 0; v < 4; ++v)
                *(f32x4*)&obuf[(m * 16 + l15) * 72 + v * 16 + g * 4] = o[v][m];
        if (lane < 16) {
#pragma unroll
            for (int m = 0; m < 4; ++m)
                lbuf[qh * 64 + m * 16 + l15] = lr[m];
        }
    }
    __syncthreads();

    if (kvh == 0) {
        const int b = bh / 12, h = bh % 12;
#pragma unroll
        for (int m = 0; m < 4; ++m) {
            float lt = lr[m] + lbuf[qh * 64 + m * 16 + l15];
            float rl = frcp(lt);
            int q = q0 + qh * 64 + m * 16 + l15;
            unsigned short* dst = AO + (size_t)(b * 1024 + q) * 768 + h * 64 + g * 4;
#pragma unroll
            for (int v = 0; v < 4; ++v) {
                f32x4 add = *(const f32x4*)&obuf[(m * 16 + l15) * 72 + v * 16 + g * 4];
                uint2 w;
                w.x = pk2((o[v][m][0] + add[0]) * rl, (o[v][m][1] + add[1]) * rl);
                w.y = pk2((o[v][m][2] + add[2]) * rl, (o[v][m][3] + add[3]) * rl);
                *(uint2*)(dst + v * 16) = w;
            }
        }
    }
#undef STAGE_TILE
}

// ---------------------------------------------------------------------------
extern "C" void kernel_launch(void* const* d_in, const int* in_sizes, int n_in,
                              void* d_out, int out_size, void* d_ws, size_t ws_size,
                              hipStream_t stream)
{
    const float* x1 = (const float*)d_in[0];
    const float* x2 = (const float*)d_in[1];
    const float* Wq = (const float*)d_in[2];
    const float* Wk = (const float*)d_in[3];
    const float* Wv = (const float*)d_in[4];
    const float* Wo = (const float*)d_in[5];
    const float* bo = (const float*)d_in[6];

    unsigned short* Wcat = (unsigned short*)d_ws;        // 2304x768
    unsigned short* Wob  = Wcat + 1769472;               // 768x768
    unsigned short* x1b  = Wob  + 589824;                // 8192x768
    unsigned short* x2b  = x1b  + 6291456;               // 8192x768
    unsigned short* Qb   = x2b  + 6291456;               // (B,H,1024,64)
    unsigned short* Kc   = Qb   + 6291456;               // (B,H,2048,64)
    unsigned short* Vt   = Kc   + 12582912;              // (B,H,64,2048)
    unsigned short* AO   = x1b;                          // alias (x1b dead)

    convert_all<<<dim3(14592), 256, 0, stream>>>(x1, x2, Wq, Wk, Wv, Wo,
                                                 x1b, x2b, Wcat, Wob);

    gemm256<<<dim3(32, 15), 512, 0, stream>>>(x1b, x2b, Wcat, Qb, Kc, Vt);

    attn_k<<<dim3(96, 8), 256, 0, stream>>>(Qb, Kc, Vt, AO);

    gemm_out<<<dim3(64, 6), 256, 0, stream>>>(AO, Wob, (float*)d_out, bo);
}

// Round 16
// 145.791 us; speedup vs baseline: 1.1381x; 1.0021x over previous
//
#include <hip/hip_runtime.h>

// ---------------------------------------------------------------------------
// PairWiseCrossAttention: B=8, N=1024, D=768, H=12, HD=64
// convert(all->bf16, exact grid) -> fused QKV+KV GEMM (256x256, 4-phase/tile,
// derived counted vmcnt) -> flash attn (kv-split waves) -> out GEMM
// (R12 configuration — best measured — with convert grid trimmed)
// ---------------------------------------------------------------------------

typedef __bf16 bf16x8 __attribute__((ext_vector_type(8)));
typedef float  f32x4  __attribute__((ext_vector_type(4)));
typedef unsigned int u32x4 __attribute__((ext_vector_type(4)));
typedef short  s16x4  __attribute__((ext_vector_type(4)));

__device__ __forceinline__ unsigned short bf16bits(float f) {
    return __builtin_bit_cast(unsigned short, (__bf16)f);
}
__device__ __forceinline__ unsigned pk2(float a, float b) {
    return (unsigned)bf16bits(a) | ((unsigned)bf16bits(b) << 16);
}
__device__ __forceinline__ bf16x8 asbf(u32x4 v) {
    return __builtin_bit_cast(bf16x8, v);
}
__device__ __forceinline__ float fexp2(float x) {
#if __has_builtin(__builtin_amdgcn_exp2f)
    return __builtin_amdgcn_exp2f(x);
#else
    return exp2f(x);
#endif
}
__device__ __forceinline__ float frcp(float x) {
#if __has_builtin(__builtin_amdgcn_rcpf)
    return __builtin_amdgcn_rcpf(x);
#else
    return 1.0f / x;
#endif
}

#define MFMA32(a, b, c) __builtin_amdgcn_mfma_f32_16x16x32_bf16((a), (b), (c), 0, 0, 0)
#define AS1(p) (const __attribute__((address_space(1))) void*)(p)
#define AS3(p) (__attribute__((address_space(3))) void*)(p)

// ---------------------------------------------------------------------------
// Convert everything to bf16 once. Flat 1D grid, no empty blocks:
//   [0, 6144)        -> x1   (1,572,864 float4)
//   [6144, 12288)    -> x2
//   [12288, 14592)   -> weights: 4 segments x 576 blocks (147,456 float4 each)
// ---------------------------------------------------------------------------
__global__ __launch_bounds__(256) void convert_all(
    const float* __restrict__ x1, const float* __restrict__ x2,
    const float* __restrict__ Wq, const float* __restrict__ Wk,
    const float* __restrict__ Wv, const float* __restrict__ Wo,
    unsigned short* __restrict__ x1b, unsigned short* __restrict__ x2b,
    unsigned short* __restrict__ Wcat, unsigned short* __restrict__ Wob)
{
    int t = blockIdx.x;
    const float* src; unsigned short* dst; int i;
    if (t < 6144) {
        src = x1; dst = x1b; i = t * 256 + threadIdx.x;
    } else if (t < 12288) {
        src = x2; dst = x2b; i = (t - 6144) * 256 + threadIdx.x;
    } else {
        int w = t - 12288;
        int seg = w / 576, blk = w - seg * 576;
        switch (seg) {
            case 0:  src = Wq; dst = Wcat;           break;
            case 1:  src = Wk; dst = Wcat +  589824; break;
            case 2:  src = Wv; dst = Wcat + 1179648; break;
            default: src = Wo; dst = Wob;            break;
        }
        i = blk * 256 + threadIdx.x;
    }
    float4 v = ((const float4*)src)[i];
    unsigned* o32 = (unsigned*)(dst + (size_t)i * 4);
    o32[0] = pk2(v.x, v.y);
    o32[1] = pk2(v.z, v.w);
}

// ---------------------------------------------------------------------------
// 256x256 projection GEMM, 4 phases/K-tile, derived counted waits (R12).
// BK=64, 12 K-tiles, 8 waves (wm 0..1 x wn 0..3), 2 LDS buffers (128 KB).
// Stage plan during tile t (for t+1, 2 loads/phase):
//   q0: A-mh0  q1,q2: B  q3: A-mh1; waits vmcnt(2) at end-q0 / end-q3.
// jb<9: A=x1b -> segq 0=Q(*0.125*log2e) 1=K1 2=V1t ; jb>=9: A=x2b -> 3=K2 4=V2t
// ---------------------------------------------------------------------------
__global__ __launch_bounds__(512, 2) void gemm256(
    const unsigned short* __restrict__ A1, const unsigned short* __restrict__ A2,
    const unsigned short* __restrict__ Wcat,
    unsigned short* __restrict__ dQ, unsigned short* __restrict__ dK,
    unsigned short* __restrict__ dV)
{
    __shared__ u32x4 smA[2][2048];   // [buf][256 rows x 8 granules] 32KB each
    __shared__ u32x4 smB[2][2048];

    const int tid  = threadIdx.x;
    const int lane = tid & 63;
    const int l15  = lane & 15;
    const int g    = lane >> 4;
    const int wid  = tid >> 6;       // 0..7
    const int wm   = wid >> 2;       // 0..1  (A half)
    const int wn   = wid & 3;        // 0..3  (B band)
    const int rb   = blockIdx.x;     // 0..31
    const int jb   = blockIdx.y;     // 0..14

    const bool br2 = (jb >= 9);
    const unsigned short* A  = br2 ? A2 : A1;
    const unsigned short* Bw = br2 ? (Wcat + 589824) : Wcat;
    const int jcol = br2 ? (jb - 9) : jb;

    f32x4 acc[8][4] = {};

#define STG_A(KT, BUF, MH, K)                                                        \
    {                                                                                \
        int s_  = wn * 64 + (K) * 256 + lane;                                        \
        int rl_ = s_ >> 3, ps_ = s_ & 7;                                             \
        const unsigned short* src_ = A +                                             \
            (size_t)(rb * 256 + wm * 128 + (MH) * 64 + rl_) * 768 +                  \
            (KT) * 64 + (ps_ ^ (rl_ & 7)) * 8;                                       \
        __builtin_amdgcn_global_load_lds(AS1(src_),                                  \
            AS3(&smA[BUF][wm * 1024 + (MH) * 512 + wn * 64 + (K) * 256]), 16, 0, 0); \
    }
#define STG_B(KT, BUF, K)                                                            \
    {                                                                                \
        int s_  = wm * 64 + (K) * 128 + lane;                                        \
        int rl_ = s_ >> 3, ps_ = s_ & 7;                                             \
        const unsigned short* src_ = Bw +                                            \
            (size_t)(jcol * 256 + wn * 64 + rl_) * 768 +                             \
            (KT) * 64 + (ps_ ^ (rl_ & 7)) * 8;                                       \
        __builtin_amdgcn_global_load_lds(AS1(src_),                                  \
            AS3(&smB[BUF][wn * 512 + wm * 64 + (K) * 128]), 16, 0, 0);               \
    }

    STG_A(0, 0, 0, 0) STG_A(0, 0, 0, 1)
    STG_B(0, 0, 0) STG_B(0, 0, 1) STG_B(0, 0, 2) STG_B(0, 0, 3)
    STG_A(0, 0, 1, 0) STG_A(0, 0, 1, 1)
    asm volatile("s_waitcnt vmcnt(0)" ::: "memory");
    __builtin_amdgcn_s_barrier();

    for (int kt = 0; kt < 12; ++kt) {
        const int buf = kt & 1;
        const int nb  = buf ^ 1;
        const bool st = (kt < 11);
        const u32x4* bA = smA[buf];
        const u32x4* bB = smB[buf];
        bf16x8 af[4], bfr[4];

        // ---------- q0: (mh0, kk0); stage A-mh0(kt+1)
#pragma unroll
        for (int n = 0; n < 4; ++n) {
            int row = wn * 64 + n * 16 + l15;
            bfr[n] = asbf(bB[row * 8 + (g ^ (row & 7))]);
        }
#pragma unroll
        for (int m = 0; m < 4; ++m) {
            int row = wm * 128 + m * 16 + l15;
            af[m] = asbf(bA[row * 8 + (g ^ (row & 7))]);
        }
        if (st) { STG_A(kt + 1, nb, 0, 0) STG_A(kt + 1, nb, 0, 1) }
        if (kt == 11) { asm volatile("s_waitcnt vmcnt(0)" ::: "memory"); }
        else          { asm volatile("s_waitcnt vmcnt(2)" ::: "memory"); }
        __builtin_amdgcn_sched_barrier(0);
        __builtin_amdgcn_s_barrier();
        __builtin_amdgcn_sched_barrier(0);
        __builtin_amdgcn_s_setprio(1);
#pragma unroll
        for (int m = 0; m < 4; ++m)
#pragma unroll
            for (int n = 0; n < 4; ++n)
                acc[m][n] = MFMA32(af[m], bfr[n], acc[m][n]);
        __builtin_amdgcn_s_setprio(0);

        // ---------- q1: (mh1, kk0); stage B(kt+1) parts 0,1
#pragma unroll
        for (int m = 0; m < 4; ++m) {
            int row = wm * 128 + 64 + m * 16 + l15;
            af[m] = asbf(bA[row * 8 + (g ^ (row & 7))]);
        }
        if (st) { STG_B(kt + 1, nb, 0) STG_B(kt + 1, nb, 1) }
        __builtin_amdgcn_sched_barrier(0);
        __builtin_amdgcn_s_barrier();
        __builtin_amdgcn_sched_barrier(0);
        __builtin_amdgcn_s_setprio(1);
#pragma unroll
        for (int m = 0; m < 4; ++m)
#pragma unroll
            for (int n = 0; n < 4; ++n)
                acc[4 + m][n] = MFMA32(af[m], bfr[n], acc[4 + m][n]);
        __builtin_amdgcn_s_setprio(0);

        // ---------- q2: (mh0, kk1); stage B(kt+1) parts 2,3
#pragma unroll
        for (int n = 0; n < 4; ++n) {
            int row = wn * 64 + n * 16 + l15;
            bfr[n] = asbf(bB[row * 8 + ((4 + g) ^ (row & 7))]);
        }
#pragma unroll
        for (int m = 0; m < 4; ++m) {
            int row = wm * 128 + m * 16 + l15;
            af[m] = asbf(bA[row * 8 + ((4 + g) ^ (row & 7))]);
        }
        if (st) { STG_B(kt + 1, nb, 2) STG_B(kt + 1, nb, 3) }
        __builtin_amdgcn_sched_barrier(0);
        __builtin_amdgcn_s_barrier();
        __builtin_amdgcn_sched_barrier(0);
        __builtin_amdgcn_s_setprio(1);
#pragma unroll
        for (int m = 0; m < 4; ++m)
#pragma unroll
            for (int n = 0; n < 4; ++n)
                acc[m][n] = MFMA32(af[m], bfr[n], acc[m][n]);
        __builtin_amdgcn_s_setprio(0);

        // ---------- q3: (mh1, kk1); stage A-mh1(kt+1); end-of-tile wait
#pragma unroll
        for (int m = 0; m < 4; ++m) {
            int row = wm * 128 + 64 + m * 16 + l15;
            af[m] = asbf(bA[row * 8 + ((4 + g) ^ (row & 7))]);
        }
        if (st) { STG_A(kt + 1, nb, 1, 0) STG_A(kt + 1, nb, 1, 1) }
        if (st) { asm volatile("s_waitcnt vmcnt(2)" ::: "memory"); }
        __builtin_amdgcn_sched_barrier(0);
        __builtin_amdgcn_s_barrier();
        __builtin_amdgcn_sched_barrier(0);
        __builtin_amdgcn_s_setprio(1);
#pragma unroll
        for (int m = 0; m < 4; ++m)
#pragma unroll
            for (int n = 0; n < 4; ++n)
                acc[4 + m][n] = MFMA32(af[m], bfr[n], acc[4 + m][n]);
        __builtin_amdgcn_s_setprio(0);
    }
#undef STG_A
#undef STG_B

    const int rloc = wm * 128 + g * 4;
    const int cloc = wn * 64 + l15;
    const int seg  = jcol / 3;
    const int segq = br2 ? seg + 3 : seg;          // 0=Q 1=K1 2=V1 3=K2 4=V2
    const int cseg = (jcol - seg * 3) * 256;
#pragma unroll
    for (int mf = 0; mf < 8; ++mf) {
#pragma unroll
        for (int n = 0; n < 4; ++n) {
            int r0 = rb * 256 + rloc + mf * 16;
            int cl = cseg + cloc + n * 16;
            int b = r0 >> 10, nn = r0 & 1023;
            int h = cl >> 6, hd = cl & 63;
            if (segq == 0) {
#pragma unroll
                for (int reg = 0; reg < 4; ++reg)
                    dQ[((size_t)(b * 12 + h) * 1024 + nn + reg) * 64 + hd] =
                        bf16bits(acc[mf][n][reg] * 0.18033688f);   // 0.125*log2(e)
            } else if (segq == 1 || segq == 3) {
                size_t koff = (segq == 3) ? 1024 : 0;
#pragma unroll
                for (int reg = 0; reg < 4; ++reg)
                    dK[((size_t)(b * 12 + h) * 2048 + koff + nn + reg) * 64 + hd] =
                        bf16bits(acc[mf][n][reg]);
            } else {
                size_t koff = (segq == 4) ? 1024 : 0;
                uint2 w;
                w.x = pk2(acc[mf][n][0], acc[mf][n][1]);
                w.y = pk2(acc[mf][n][2], acc[mf][n][3]);
                *(uint2*)(dV + ((size_t)(b * 12 + h) * 64 + hd) * 2048 +
                          koff + nn) = w;
            }
        }
    }
}

// ---------------------------------------------------------------------------
// 128x128 2-phase GEMM for the output projection: C = AO . Wo^T + bo (fp32).
// ---------------------------------------------------------------------------
__global__ __launch_bounds__(256) void gemm_out(
    const unsigned short* __restrict__ A, const unsigned short* __restrict__ Bw,
    float* __restrict__ dO, const float* __restrict__ bias)
{
    __shared__ u32x4 smA[2048];
    __shared__ u32x4 smB[2048];

    const int tid  = threadIdx.x;
    const int lane = tid & 63;
    const int l15  = lane & 15;
    const int g    = lane >> 4;
    const int wid  = tid >> 6;
    const int rb   = blockIdx.x;
    const int jb   = blockIdx.y;
    const int wr   = (wid >> 1) * 64;
    const int wc   = (wid & 1) * 64;

    f32x4 acc[4][4] = {};

#define GSTAGE(KT, BO)                                                               \
    {                                                                                \
        int kt_ = (KT);                                                              \
        _Pragma("unroll")                                                            \
        for (int c_ = 0; c_ < 4; ++c_) {                                             \
            int i_   = (wid + c_ * 4) * 64 + lane;                                   \
            int row_ = i_ >> 3;                                                      \
            int gs_  = (i_ & 7) ^ (row_ & 7);                                        \
            const unsigned short* sa = A +                                           \
                (size_t)(rb * 128 + row_) * 768 + kt_ * 64 + gs_ * 8;                \
            __builtin_amdgcn_global_load_lds(AS1(sa),                                \
                AS3(smA + (BO) + (wid + c_ * 4) * 64), 16, 0, 0);                    \
            const unsigned short* sb = Bw +                                          \
                (size_t)(jb * 128 + row_) * 768 + kt_ * 64 + gs_ * 8;                \
            __builtin_amdgcn_global_load_lds(AS1(sb),                                \
                AS3(smB + (BO) + (wid + c_ * 4) * 64), 16, 0, 0);                    \
        }                                                                            \
    }

    GSTAGE(0, 0)

    for (int kt = 0; kt < 12; ++kt) {
        __builtin_amdgcn_s_barrier();
        if (kt < 11) {
            GSTAGE(kt + 1, ((kt + 1) & 1) << 10)
            asm volatile("s_waitcnt vmcnt(8)" ::: "memory");
        } else {
            asm volatile("s_waitcnt vmcnt(0)" ::: "memory");
        }
        __builtin_amdgcn_s_barrier();
        __builtin_amdgcn_sched_barrier(0);

        const u32x4* bA = smA + ((kt & 1) << 10);
        const u32x4* bB = smB + ((kt & 1) << 10);

#pragma unroll
        for (int kk = 0; kk < 2; ++kk) {
            bf16x8 af[4], bfr[4];
#pragma unroll
            for (int m = 0; m < 4; ++m) {
                int row = wr + m * 16 + l15;
                af[m] = asbf(bA[row * 8 + ((kk * 4 + g) ^ (row & 7))]);
            }
#pragma unroll
            for (int n = 0; n < 4; ++n) {
                int row = wc + n * 16 + l15;
                bfr[n] = asbf(bB[row * 8 + ((kk * 4 + g) ^ (row & 7))]);
            }
#pragma unroll
            for (int m = 0; m < 4; ++m)
#pragma unroll
                for (int n = 0; n < 4; ++n)
                    acc[m][n] = MFMA32(af[m], bfr[n], acc[m][n]);
        }
    }
#undef GSTAGE

    const int rloc = wr + g * 4;
    const int cloc = wc + l15;
#pragma unroll
    for (int m = 0; m < 4; ++m)
#pragma unroll
        for (int n = 0; n < 4; ++n) {
            int r0 = rb * 128 + rloc + m * 16;
            int c  = jb * 128 + cloc + n * 16;
#pragma unroll
            for (int reg = 0; reg < 4; ++reg)
                dO[(size_t)(r0 + reg) * 768 + c] = acc[m][n][reg] + bias[c];
        }
}

// ---------------------------------------------------------------------------
// Flash attention (R12 exact — best measured). kv-split waves:
// wave (qh,kvh) computes q-half qh (64 q) x kv-half kvh (32 kv); half the
// LDS reads of the duplicated form. Fixed-max softmax (p = 2^s, order-free)
// -> O,l additive over kv, combined once at the end via the dead staging LDS.
// ---------------------------------------------------------------------------
__global__ __launch_bounds__(256, 3) void attn_k(
    const unsigned short* __restrict__ Q, const unsigned short* __restrict__ K,
    const unsigned short* __restrict__ Vt, unsigned short* __restrict__ AO)
{
    __shared__ u32x4 sK[1536];              // 3 bufs x (64 rows x 8 granules)
    __shared__ u32x4 sV[1536];

    const int tid  = threadIdx.x;
    const int lane = tid & 63;
    const int g    = lane >> 4;
    const int l15  = lane & 15;
    const int wid  = tid >> 6;
    const int qh   = wid & 1;               // q half (64 q each)
    const int kvh  = wid >> 1;              // kv half (32 kv each)
    const int bh   = blockIdx.x;            // fastest -> XCD = bh % 8
    const int q0   = blockIdx.y * 128;

    const unsigned short* Qh = Q  + (size_t)bh * (1024 * 64);
    const unsigned short* Kh = K  + (size_t)bh * (2048 * 64);
    const unsigned short* Vh = Vt + (size_t)bh * (64 * 2048);

    bf16x8 qf[4][2];
#pragma unroll
    for (int m = 0; m < 4; ++m)
#pragma unroll
        for (int kk = 0; kk < 2; ++kk)
            qf[m][kk] = *(const bf16x8*)(Qh +
                (size_t)(q0 + qh * 64 + m * 16 + l15) * 64 + kk * 32 + g * 8);

    f32x4 o[4][4] = {};                     // [v hd-frag][m q-frag], kv-partial
    float lr[4] = {0.f, 0.f, 0.f, 0.f};

#define STAGE_TILE(T, DOFF)                                                          \
    {                                                                                \
        int t_ = (T);                                                                \
        _Pragma("unroll")                                                            \
        for (int c_ = 0; c_ < 2; ++c_) {                                             \
            int i_   = (wid + c_ * 4) * 64 + lane;                                   \
            int row_ = i_ >> 3;                                                      \
            int gsK_ = (i_ & 7) ^ ((row_ & 3) | ((row_ >> 1) & 4));                  \
            int gsV_ = (i_ & 7) ^ (row_ & 7);                                        \
            const unsigned short* srcK_ = Kh + ((size_t)t_ * 64 + row_) * 64 + gsK_ * 8; \
            __builtin_amdgcn_global_load_lds(AS1(srcK_),                             \
                AS3(sK + (DOFF) + (wid + c_ * 4) * 64), 16, 0, 0);                   \
            const unsigned short* srcV_ = Vh + (size_t)row_ * 2048 + t_ * 64 + gsV_ * 8; \
            __builtin_amdgcn_global_load_lds(AS1(srcV_),                             \
                AS3(sV + (DOFF) + (wid + c_ * 4) * 64), 16, 0, 0);                   \
        }                                                                            \
    }

    STAGE_TILE(0, 0)
    STAGE_TILE(1, 512)

    for (int t = 0; t < 32; ++t) {
        if (t < 31) { asm volatile("s_waitcnt vmcnt(4)" ::: "memory"); }
        else        { asm volatile("s_waitcnt vmcnt(0)" ::: "memory"); }
        __builtin_amdgcn_s_barrier();
        if (t < 30) {
            STAGE_TILE(t + 2, ((t + 2) % 3) * 512)
        }
        __builtin_amdgcn_sched_barrier(0);

        const u32x4* sKb = sK + (t % 3) * 512;
        const u32x4* sVb = sV + (t % 3) * 512;

        f32x4 s[2][4] = {};
        __builtin_amdgcn_s_setprio(1);
#pragma unroll
        for (int kk = 0; kk < 2; ++kk) {
            bf16x8 kf[2];
#pragma unroll
            for (int j = 0; j < 2; ++j) {
                int rowp = (kvh << 5) + ((l15 >> 2) << 3) + (j << 2) + (l15 & 3);
                kf[j] = asbf(sKb[rowp * 8 + ((kk * 4 + g) ^ (l15 & 7))]);
            }
#pragma unroll
            for (int j = 0; j < 2; ++j)
#pragma unroll
                for (int m = 0; m < 4; ++m)
                    s[j][m] = MFMA32(kf[j], qf[m][kk], s[j][m]);
        }
        __builtin_amdgcn_s_setprio(0);

        s16x4 p16[2][4];
#pragma unroll
        for (int m = 0; m < 4; ++m) {
            float p0 = fexp2(s[0][m][0]), p1 = fexp2(s[0][m][1]);
            float p2 = fexp2(s[0][m][2]), p3 = fexp2(s[0][m][3]);
            float p4 = fexp2(s[1][m][0]), p5 = fexp2(s[1][m][1]);
            float p6 = fexp2(s[1][m][2]), p7 = fexp2(s[1][m][3]);
            lr[m] += (p0 + p1) + (p2 + p3) + (p4 + p5) + (p6 + p7);
            p16[0][m] = (s16x4){ (short)bf16bits(p0), (short)bf16bits(p1),
                                 (short)bf16bits(p2), (short)bf16bits(p3) };
            p16[1][m] = (s16x4){ (short)bf16bits(p4), (short)bf16bits(p5),
                                 (short)bf16bits(p6), (short)bf16bits(p7) };
        }

        __builtin_amdgcn_s_setprio(1);
        bf16x8 pf[4];
#pragma unroll
        for (int m = 0; m < 4; ++m)
            pf[m] = __builtin_bit_cast(bf16x8,
                __builtin_shufflevector(p16[0][m], p16[1][m],
                                        0, 1, 2, 3, 4, 5, 6, 7));
#pragma unroll
        for (int v = 0; v < 4; ++v) {
            int row = v * 16 + l15;
            bf16x8 vf = asbf(sVb[row * 8 + ((kvh * 4 + g) ^ (row & 7))]);
#pragma unroll
            for (int m = 0; m < 4; ++m)
                o[v][m] = MFMA32(vf, pf[m], o[v][m]);
        }
        __builtin_amdgcn_s_setprio(0);
    }

    // combine kv-halves through the (now dead) staging LDS
#pragma unroll
    for (int m = 0; m < 4; ++m) {
        lr[m] += __shfl_xor(lr[m], 16);
        lr[m] += __shfl_xor(lr[m], 32);
    }
    __syncthreads();

    float* oK   = (float*)sK;
    float* oVf  = (float*)sV;
    float* obuf = qh ? oVf : oK;
    float* lbuf = oVf + 64 * 72;

    if (kvh == 1) {
#pragma unroll
        for (int m = 0; m < 4; ++m)
#pragma unroll
            for (int v = 0; v < 4; ++v)
                *(f32x4*)&obuf[(m * 16 + l15) * 72 + v * 16 + g * 4] = o[v][m];
        if (lane < 16) {
#pragma unroll
            for (int m = 0; m < 4; ++m)
                lbuf[qh * 64 + m * 16 + l15] = lr[m];
        }
    }
    __syncthreads();

    if (kvh == 0) {
        const int b = bh / 12, h = bh % 12;
#pragma unroll
        for (int m = 0; m < 4; ++m) {
            float lt = lr[m] + lbuf[qh * 64 + m * 16 + l15];
            float rl = frcp(lt);
            int q = q0 + qh * 64 + m * 16 + l15;
            unsigned short* dst = AO + (size_t)(b * 1024 + q) * 768 + h * 64 + g * 4;
#pragma unroll
            for (int v = 0; v < 4; ++v) {
                f32x4 add = *(const f32x4*)&obuf[(m * 16 + l15) * 72 + v * 16 + g * 4];
                uint2 w;
                w.x = pk2((o[v][m][0] + add[0]) * rl, (o[v][m][1] + add[1]) * rl);
                w.y = pk2((o[v][m][2] + add[2]) * rl, (o[v][m][3] + add[3]) * rl);
                *(uint2*)(dst + v * 16) = w;
            }
        }
    }
#undef STAGE_TILE
}

// ---------------------------------------------------------------------------
extern "C" void kernel_launch(void* const* d_in, const int* in_sizes, int n_in,
                              void* d_out, int out_size, void* d_ws, size_t ws_size,
                              hipStream_t stream)
{
    const float* x1 = (const float*)d_in[0];
    const float* x2 = (const float*)d_in[1];
    const float* Wq = (const float*)d_in[2];
    const float* Wk = (const float*)d_in[3];
    const float* Wv = (const float*)d_in[4];
    const float* Wo = (const float*)d_in[5];
    const float* bo = (const float*)d_in[6];

    unsigned short* Wcat = (unsigned short*)d_ws;        // 2304x768
    unsigned short* Wob  = Wcat + 1769472;               // 768x768
    unsigned short* x1b  = Wob  + 589824;                // 8192x768
    unsigned short* x2b  = x1b  + 6291456;               // 8192x768
    unsigned short* Qb   = x2b  + 6291456;               // (B,H,1024,64)
    unsigned short* Kc   = Qb   + 6291456;               // (B,H,2048,64)
    unsigned short* Vt   = Kc   + 12582912;              // (B,H,64,2048)
    unsigned short* AO   = x1b;                          // alias (x1b dead)

    convert_all<<<dim3(14592), 256, 0, stream>>>(x1, x2, Wq, Wk, Wv, Wo,
                                                 x1b, x2b, Wcat, Wob);

    gemm256<<<dim3(32, 15), 512, 0, stream>>>(x1b, x2b, Wcat, Qb, Kc, Vt);

    attn_k<<<dim3(96, 8), 256, 0, stream>>>(Qb, Kc, Vt, AO);

    gemm_out<<<dim3(64, 6), 256, 0, stream>>>(AO, Wob, (float*)d_out, bo);
}

// Round 17
// 145.600 us; speedup vs baseline: 1.1396x; 1.0013x over previous
//
#include <hip/hip_runtime.h>

// ---------------------------------------------------------------------------
// PairWiseCrossAttention: B=8, N=1024, D=768, H=12, HD=64
// convert(all->bf16, exact grid) -> fused QKV+KV GEMM (256x256, 4-phase/tile,
// derived counted vmcnt) -> flash attn (kv-split waves) -> out GEMM
// (R12 configuration — best measured — with convert grid trimmed)
// ---------------------------------------------------------------------------

typedef __bf16 bf16x8 __attribute__((ext_vector_type(8)));
typedef float  f32x4  __attribute__((ext_vector_type(4)));
typedef unsigned int u32x4 __attribute__((ext_vector_type(4)));
typedef short  s16x4  __attribute__((ext_vector_type(4)));

__device__ __forceinline__ unsigned short bf16bits(float f) {
    return __builtin_bit_cast(unsigned short, (__bf16)f);
}
__device__ __forceinline__ unsigned pk2(float a, float b) {
    return (unsigned)bf16bits(a) | ((unsigned)bf16bits(b) << 16);
}
__device__ __forceinline__ bf16x8 asbf(u32x4 v) {
    return __builtin_bit_cast(bf16x8, v);
}
__device__ __forceinline__ float fexp2(float x) {
#if __has_builtin(__builtin_amdgcn_exp2f)
    return __builtin_amdgcn_exp2f(x);
#else
    return exp2f(x);
#endif
}
__device__ __forceinline__ float frcp(float x) {
#if __has_builtin(__builtin_amdgcn_rcpf)
    return __builtin_amdgcn_rcpf(x);
#else
    return 1.0f / x;
#endif
}

#define MFMA32(a, b, c) __builtin_amdgcn_mfma_f32_16x16x32_bf16((a), (b), (c), 0, 0, 0)
#define AS1(p) (const __attribute__((address_space(1))) void*)(p)
#define AS3(p) (__attribute__((address_space(3))) void*)(p)

// ---------------------------------------------------------------------------
// Convert everything to bf16 once. Flat 1D grid, no empty blocks:
//   [0, 6144)        -> x1   (1,572,864 float4)
//   [6144, 12288)    -> x2
//   [12288, 14592)   -> weights: 4 segments x 576 blocks (147,456 float4 each)
// ---------------------------------------------------------------------------
__global__ __launch_bounds__(256) void convert_all(
    const float* __restrict__ x1, const float* __restrict__ x2,
    const float* __restrict__ Wq, const float* __restrict__ Wk,
    const float* __restrict__ Wv, const float* __restrict__ Wo,
    unsigned short* __restrict__ x1b, unsigned short* __restrict__ x2b,
    unsigned short* __restrict__ Wcat, unsigned short* __restrict__ Wob)
{
    int t = blockIdx.x;
    const float* src; unsigned short* dst; int i;
    if (t < 6144) {
        src = x1; dst = x1b; i = t * 256 + threadIdx.x;
    } else if (t < 12288) {
        src = x2; dst = x2b; i = (t - 6144) * 256 + threadIdx.x;
    } else {
        int w = t - 12288;
        int seg = w / 576, blk = w - seg * 576;
        switch (seg) {
            case 0:  src = Wq; dst = Wcat;           break;
            case 1:  src = Wk; dst = Wcat +  589824; break;
            case 2:  src = Wv; dst = Wcat + 1179648; break;
            default: src = Wo; dst = Wob;            break;
        }
        i = blk * 256 + threadIdx.x;
    }
    float4 v = ((const float4*)src)[i];
    unsigned* o32 = (unsigned*)(dst + (size_t)i * 4);
    o32[0] = pk2(v.x, v.y);
    o32[1] = pk2(v.z, v.w);
}

// ---------------------------------------------------------------------------
// 256x256 projection GEMM, 4 phases/K-tile, derived counted waits (R12).
// BK=64, 12 K-tiles, 8 waves (wm 0..1 x wn 0..3), 2 LDS buffers (128 KB).
// Stage plan during tile t (for t+1, 2 loads/phase):
//   q0: A-mh0  q1,q2: B  q3: A-mh1; waits vmcnt(2) at end-q0 / end-q3.
// jb<9: A=x1b -> segq 0=Q(*0.125*log2e) 1=K1 2=V1t ; jb>=9: A=x2b -> 3=K2 4=V2t
// ---------------------------------------------------------------------------
__global__ __launch_bounds__(512, 2) void gemm256(
    const unsigned short* __restrict__ A1, const unsigned short* __restrict__ A2,
    const unsigned short* __restrict__ Wcat,
    unsigned short* __restrict__ dQ, unsigned short* __restrict__ dK,
    unsigned short* __restrict__ dV)
{
    __shared__ u32x4 smA[2][2048];   // [buf][256 rows x 8 granules] 32KB each
    __shared__ u32x4 smB[2][2048];

    const int tid  = threadIdx.x;
    const int lane = tid & 63;
    const int l15  = lane & 15;
    const int g    = lane >> 4;
    const int wid  = tid >> 6;       // 0..7
    const int wm   = wid >> 2;       // 0..1  (A half)
    const int wn   = wid & 3;        // 0..3  (B band)
    const int rb   = blockIdx.x;     // 0..31
    const int jb   = blockIdx.y;     // 0..14

    const bool br2 = (jb >= 9);
    const unsigned short* A  = br2 ? A2 : A1;
    const unsigned short* Bw = br2 ? (Wcat + 589824) : Wcat;
    const int jcol = br2 ? (jb - 9) : jb;

    f32x4 acc[8][4] = {};

#define STG_A(KT, BUF, MH, K)                                                        \
    {                                                                                \
        int s_  = wn * 64 + (K) * 256 + lane;                                        \
        int rl_ = s_ >> 3, ps_ = s_ & 7;                                             \
        const unsigned short* src_ = A +                                             \
            (size_t)(rb * 256 + wm * 128 + (MH) * 64 + rl_) * 768 +                  \
            (KT) * 64 + (ps_ ^ (rl_ & 7)) * 8;                                       \
        __builtin_amdgcn_global_load_lds(AS1(src_),                                  \
            AS3(&smA[BUF][wm * 1024 + (MH) * 512 + wn * 64 + (K) * 256]), 16, 0, 0); \
    }
#define STG_B(KT, BUF, K)                                                            \
    {                                                                                \
        int s_  = wm * 64 + (K) * 128 + lane;                                        \
        int rl_ = s_ >> 3, ps_ = s_ & 7;                                             \
        const unsigned short* src_ = Bw +                                            \
            (size_t)(jcol * 256 + wn * 64 + rl_) * 768 +                             \
            (KT) * 64 + (ps_ ^ (rl_ & 7)) * 8;                                       \
        __builtin_amdgcn_global_load_lds(AS1(src_),                                  \
            AS3(&smB[BUF][wn * 512 + wm * 64 + (K) * 128]), 16, 0, 0);               \
    }

    STG_A(0, 0, 0, 0) STG_A(0, 0, 0, 1)
    STG_B(0, 0, 0) STG_B(0, 0, 1) STG_B(0, 0, 2) STG_B(0, 0, 3)
    STG_A(0, 0, 1, 0) STG_A(0, 0, 1, 1)
    asm volatile("s_waitcnt vmcnt(0)" ::: "memory");
    __builtin_amdgcn_s_barrier();

    for (int kt = 0; kt < 12; ++kt) {
        const int buf = kt & 1;
        const int nb  = buf ^ 1;
        const bool st = (kt < 11);
        const u32x4* bA = smA[buf];
        const u32x4* bB = smB[buf];
        bf16x8 af[4], bfr[4];

        // ---------- q0: (mh0, kk0); stage A-mh0(kt+1)
#pragma unroll
        for (int n = 0; n < 4; ++n) {
            int row = wn * 64 + n * 16 + l15;
            bfr[n] = asbf(bB[row * 8 + (g ^ (row & 7))]);
        }
#pragma unroll
        for (int m = 0; m < 4; ++m) {
            int row = wm * 128 + m * 16 + l15;
            af[m] = asbf(bA[row * 8 + (g ^ (row & 7))]);
        }
        if (st) { STG_A(kt + 1, nb, 0, 0) STG_A(kt + 1, nb, 0, 1) }
        if (kt == 11) { asm volatile("s_waitcnt vmcnt(0)" ::: "memory"); }
        else          { asm volatile("s_waitcnt vmcnt(2)" ::: "memory"); }
        __builtin_amdgcn_sched_barrier(0);
        __builtin_amdgcn_s_barrier();
        __builtin_amdgcn_sched_barrier(0);
        __builtin_amdgcn_s_setprio(1);
#pragma unroll
        for (int m = 0; m < 4; ++m)
#pragma unroll
            for (int n = 0; n < 4; ++n)
                acc[m][n] = MFMA32(af[m], bfr[n], acc[m][n]);
        __builtin_amdgcn_s_setprio(0);

        // ---------- q1: (mh1, kk0); stage B(kt+1) parts 0,1
#pragma unroll
        for (int m = 0; m < 4; ++m) {
            int row = wm * 128 + 64 + m * 16 + l15;
            af[m] = asbf(bA[row * 8 + (g ^ (row & 7))]);
        }
        if (st) { STG_B(kt + 1, nb, 0) STG_B(kt + 1, nb, 1) }
        __builtin_amdgcn_sched_barrier(0);
        __builtin_amdgcn_s_barrier();
        __builtin_amdgcn_sched_barrier(0);
        __builtin_amdgcn_s_setprio(1);
#pragma unroll
        for (int m = 0; m < 4; ++m)
#pragma unroll
            for (int n = 0; n < 4; ++n)
                acc[4 + m][n] = MFMA32(af[m], bfr[n], acc[4 + m][n]);
        __builtin_amdgcn_s_setprio(0);

        // ---------- q2: (mh0, kk1); stage B(kt+1) parts 2,3
#pragma unroll
        for (int n = 0; n < 4; ++n) {
            int row = wn * 64 + n * 16 + l15;
            bfr[n] = asbf(bB[row * 8 + ((4 + g) ^ (row & 7))]);
        }
#pragma unroll
        for (int m = 0; m < 4; ++m) {
            int row = wm * 128 + m * 16 + l15;
            af[m] = asbf(bA[row * 8 + ((4 + g) ^ (row & 7))]);
        }
        if (st) { STG_B(kt + 1, nb, 2) STG_B(kt + 1, nb, 3) }
        __builtin_amdgcn_sched_barrier(0);
        __builtin_amdgcn_s_barrier();
        __builtin_amdgcn_sched_barrier(0);
        __builtin_amdgcn_s_setprio(1);
#pragma unroll
        for (int m = 0; m < 4; ++m)
#pragma unroll
            for (int n = 0; n < 4; ++n)
                acc[m][n] = MFMA32(af[m], bfr[n], acc[m][n]);
        __builtin_amdgcn_s_setprio(0);

        // ---------- q3: (mh1, kk1); stage A-mh1(kt+1); end-of-tile wait
#pragma unroll
        for (int m = 0; m < 4; ++m) {
            int row = wm * 128 + 64 + m * 16 + l15;
            af[m] = asbf(bA[row * 8 + ((4 + g) ^ (row & 7))]);
        }
        if (st) { STG_A(kt + 1, nb, 1, 0) STG_A(kt + 1, nb, 1, 1) }
        if (st) { asm volatile("s_waitcnt vmcnt(2)" ::: "memory"); }
        __builtin_amdgcn_sched_barrier(0);
        __builtin_amdgcn_s_barrier();
        __builtin_amdgcn_sched_barrier(0);
        __builtin_amdgcn_s_setprio(1);
#pragma unroll
        for (int m = 0; m < 4; ++m)
#pragma unroll
            for (int n = 0; n < 4; ++n)
                acc[4 + m][n] = MFMA32(af[m], bfr[n], acc[4 + m][n]);
        __builtin_amdgcn_s_setprio(0);
    }
#undef STG_A
#undef STG_B

    const int rloc = wm * 128 + g * 4;
    const int cloc = wn * 64 + l15;
    const int seg  = jcol / 3;
    const int segq = br2 ? seg + 3 : seg;          // 0=Q 1=K1 2=V1 3=K2 4=V2
    const int cseg = (jcol - seg * 3) * 256;
#pragma unroll
    for (int mf = 0; mf < 8; ++mf) {
#pragma unroll
        for (int n = 0; n < 4; ++n) {
            int r0 = rb * 256 + rloc + mf * 16;
            int cl = cseg + cloc + n * 16;
            int b = r0 >> 10, nn = r0 & 1023;
            int h = cl >> 6, hd = cl & 63;
            if (segq == 0) {
#pragma unroll
                for (int reg = 0; reg < 4; ++reg)
                    dQ[((size_t)(b * 12 + h) * 1024 + nn + reg) * 64 + hd] =
                        bf16bits(acc[mf][n][reg] * 0.18033688f);   // 0.125*log2(e)
            } else if (segq == 1 || segq == 3) {
                size_t koff = (segq == 3) ? 1024 : 0;
#pragma unroll
                for (int reg = 0; reg < 4; ++reg)
                    dK[((size_t)(b * 12 + h) * 2048 + koff + nn + reg) * 64 + hd] =
                        bf16bits(acc[mf][n][reg]);
            } else {
                size_t koff = (segq == 4) ? 1024 : 0;
                uint2 w;
                w.x = pk2(acc[mf][n][0], acc[mf][n][1]);
                w.y = pk2(acc[mf][n][2], acc[mf][n][3]);
                *(uint2*)(dV + ((size_t)(b * 12 + h) * 64 + hd) * 2048 +
                          koff + nn) = w;
            }
        }
    }
}

// ---------------------------------------------------------------------------
// 128x128 2-phase GEMM for the output projection: C = AO . Wo^T + bo (fp32).
// ---------------------------------------------------------------------------
__global__ __launch_bounds__(256) void gemm_out(
    const unsigned short* __restrict__ A, const unsigned short* __restrict__ Bw,
    float* __restrict__ dO, const float* __restrict__ bias)
{
    __shared__ u32x4 smA[2048];
    __shared__ u32x4 smB[2048];

    const int tid  = threadIdx.x;
    const int lane = tid & 63;
    const int l15  = lane & 15;
    const int g    = lane >> 4;
    const int wid  = tid >> 6;
    const int rb   = blockIdx.x;
    const int jb   = blockIdx.y;
    const int wr   = (wid >> 1) * 64;
    const int wc   = (wid & 1) * 64;

    f32x4 acc[4][4] = {};

#define GSTAGE(KT, BO)                                                               \
    {                                                                                \
        int kt_ = (KT);                                                              \
        _Pragma("unroll")                                                            \
        for (int c_ = 0; c_ < 4; ++c_) {                                             \
            int i_   = (wid + c_ * 4) * 64 + lane;                                   \
            int row_ = i_ >> 3;                                                      \
            int gs_  = (i_ & 7) ^ (row_ & 7);                                        \
            const unsigned short* sa = A +                                           \
                (size_t)(rb * 128 + row_) * 768 + kt_ * 64 + gs_ * 8;                \
            __builtin_amdgcn_global_load_lds(AS1(sa),                                \
                AS3(smA + (BO) + (wid + c_ * 4) * 64), 16, 0, 0);                    \
            const unsigned short* sb = Bw +                                          \
                (size_t)(jb * 128 + row_) * 768 + kt_ * 64 + gs_ * 8;                \
            __builtin_amdgcn_global_load_lds(AS1(sb),                                \
                AS3(smB + (BO) + (wid + c_ * 4) * 64), 16, 0, 0);                    \
        }                                                                            \
    }

    GSTAGE(0, 0)

    for (int kt = 0; kt < 12; ++kt) {
        __builtin_amdgcn_s_barrier();
        if (kt < 11) {
            GSTAGE(kt + 1, ((kt + 1) & 1) << 10)
            asm volatile("s_waitcnt vmcnt(8)" ::: "memory");
        } else {
            asm volatile("s_waitcnt vmcnt(0)" ::: "memory");
        }
        __builtin_amdgcn_s_barrier();
        __builtin_amdgcn_sched_barrier(0);

        const u32x4* bA = smA + ((kt & 1) << 10);
        const u32x4* bB = smB + ((kt & 1) << 10);

#pragma unroll
        for (int kk = 0; kk < 2; ++kk) {
            bf16x8 af[4], bfr[4];
#pragma unroll
            for (int m = 0; m < 4; ++m) {
                int row = wr + m * 16 + l15;
                af[m] = asbf(bA[row * 8 + ((kk * 4 + g) ^ (row & 7))]);
            }
#pragma unroll
            for (int n = 0; n < 4; ++n) {
                int row = wc + n * 16 + l15;
                bfr[n] = asbf(bB[row * 8 + ((kk * 4 + g) ^ (row & 7))]);
            }
#pragma unroll
            for (int m = 0; m < 4; ++m)
#pragma unroll
                for (int n = 0; n < 4; ++n)
                    acc[m][n] = MFMA32(af[m], bfr[n], acc[m][n]);
        }
    }
#undef GSTAGE

    const int rloc = wr + g * 4;
    const int cloc = wc + l15;
#pragma unroll
    for (int m = 0; m < 4; ++m)
#pragma unroll
        for (int n = 0; n < 4; ++n) {
            int r0 = rb * 128 + rloc + m * 16;
            int c  = jb * 128 + cloc + n * 16;
#pragma unroll
            for (int reg = 0; reg < 4; ++reg)
                dO[(size_t)(r0 + reg) * 768 + c] = acc[m][n][reg] + bias[c];
        }
}

// ---------------------------------------------------------------------------
// Flash attention (R12 exact — best measured). kv-split waves:
// wave (qh,kvh) computes q-half qh (64 q) x kv-half kvh (32 kv); half the
// LDS reads of the duplicated form. Fixed-max softmax (p = 2^s, order-free)
// -> O,l additive over kv, combined once at the end via the dead staging LDS.
// ---------------------------------------------------------------------------
__global__ __launch_bounds__(256, 3) void attn_k(
    const unsigned short* __restrict__ Q, const unsigned short* __restrict__ K,
    const unsigned short* __restrict__ Vt, unsigned short* __restrict__ AO)
{
    __shared__ u32x4 sK[1536];              // 3 bufs x (64 rows x 8 granules)
    __shared__ u32x4 sV[1536];

    const int tid  = threadIdx.x;
    const int lane = tid & 63;
    const int g    = lane >> 4;
    const int l15  = lane & 15;
    const int wid  = tid >> 6;
    const int qh   = wid & 1;               // q half (64 q each)
    const int kvh  = wid >> 1;              // kv half (32 kv each)
    const int bh   = blockIdx.x;            // fastest -> XCD = bh % 8
    const int q0   = blockIdx.y * 128;

    const unsigned short* Qh = Q  + (size_t)bh * (1024 * 64);
    const unsigned short* Kh = K  + (size_t)bh * (2048 * 64);
    const unsigned short* Vh = Vt + (size_t)bh * (64 * 2048);

    bf16x8 qf[4][2];
#pragma unroll
    for (int m = 0; m < 4; ++m)
#pragma unroll
        for (int kk = 0; kk < 2; ++kk)
            qf[m][kk] = *(const bf16x8*)(Qh +
                (size_t)(q0 + qh * 64 + m * 16 + l15) * 64 + kk * 32 + g * 8);

    f32x4 o[4][4] = {};                     // [v hd-frag][m q-frag], kv-partial
    float lr[4] = {0.f, 0.f, 0.f, 0.f};

#define STAGE_TILE(T, DOFF)                                                          \
    {                                                                                \
        int t_ = (T);                                                                \
        _Pragma("unroll")                                                            \
        for (int c_ = 0; c_ < 2; ++c_) {                                             \
            int i_   = (wid + c_ * 4) * 64 + lane;                                   \
            int row_ = i_ >> 3;                                                      \
            int gsK_ = (i_ & 7) ^ ((row_ & 3) | ((row_ >> 1) & 4));                  \
            int gsV_ = (i_ & 7) ^ (row_ & 7);                                        \
            const unsigned short* srcK_ = Kh + ((size_t)t_ * 64 + row_) * 64 + gsK_ * 8; \
            __builtin_amdgcn_global_load_lds(AS1(srcK_),                             \
                AS3(sK + (DOFF) + (wid + c_ * 4) * 64), 16, 0, 0);                   \
            const unsigned short* srcV_ = Vh + (size_t)row_ * 2048 + t_ * 64 + gsV_ * 8; \
            __builtin_amdgcn_global_load_lds(AS1(srcV_),                             \
                AS3(sV + (DOFF) + (wid + c_ * 4) * 64), 16, 0, 0);                   \
        }                                                                            \
    }

    STAGE_TILE(0, 0)
    STAGE_TILE(1, 512)

    for (int t = 0; t < 32; ++t) {
        if (t < 31) { asm volatile("s_waitcnt vmcnt(4)" ::: "memory"); }
        else        { asm volatile("s_waitcnt vmcnt(0)" ::: "memory"); }
        __builtin_amdgcn_s_barrier();
        if (t < 30) {
            STAGE_TILE(t + 2, ((t + 2) % 3) * 512)
        }
        __builtin_amdgcn_sched_barrier(0);

        const u32x4* sKb = sK + (t % 3) * 512;
        const u32x4* sVb = sV + (t % 3) * 512;

        f32x4 s[2][4] = {};
        __builtin_amdgcn_s_setprio(1);
#pragma unroll
        for (int kk = 0; kk < 2; ++kk) {
            bf16x8 kf[2];
#pragma unroll
            for (int j = 0; j < 2; ++j) {
                int rowp = (kvh << 5) + ((l15 >> 2) << 3) + (j << 2) + (l15 & 3);
                kf[j] = asbf(sKb[rowp * 8 + ((kk * 4 + g) ^ (l15 & 7))]);
            }
#pragma unroll
            for (int j = 0; j < 2; ++j)
#pragma unroll
                for (int m = 0; m < 4; ++m)
                    s[j][m] = MFMA32(kf[j], qf[m][kk], s[j][m]);
        }
        __builtin_amdgcn_s_setprio(0);

        s16x4 p16[2][4];
#pragma unroll
        for (int m = 0; m < 4; ++m) {
            float p0 = fexp2(s[0][m][0]), p1 = fexp2(s[0][m][1]);
            float p2 = fexp2(s[0][m][2]), p3 = fexp2(s[0][m][3]);
            float p4 = fexp2(s[1][m][0]), p5 = fexp2(s[1][m][1]);
            float p6 = fexp2(s[1][m][2]), p7 = fexp2(s[1][m][3]);
            lr[m] += (p0 + p1) + (p2 + p3) + (p4 + p5) + (p6 + p7);
            p16[0][m] = (s16x4){ (short)bf16bits(p0), (short)bf16bits(p1),
                                 (short)bf16bits(p2), (short)bf16bits(p3) };
            p16[1][m] = (s16x4){ (short)bf16bits(p4), (short)bf16bits(p5),
                                 (short)bf16bits(p6), (short)bf16bits(p7) };
        }

        __builtin_amdgcn_s_setprio(1);
        bf16x8 pf[4];
#pragma unroll
        for (int m = 0; m < 4; ++m)
            pf[m] = __builtin_bit_cast(bf16x8,
                __builtin_shufflevector(p16[0][m], p16[1][m],
                                        0, 1, 2, 3, 4, 5, 6, 7));
#pragma unroll
        for (int v = 0; v < 4; ++v) {
            int row = v * 16 + l15;
            bf16x8 vf = asbf(sVb[row * 8 + ((kvh * 4 + g) ^ (row & 7))]);
#pragma unroll
            for (int m = 0; m < 4; ++m)
                o[v][m] = MFMA32(vf, pf[m], o[v][m]);
        }
        __builtin_amdgcn_s_setprio(0);
    }

    // combine kv-halves through the (now dead) staging LDS
#pragma unroll
    for (int m = 0; m < 4; ++m) {
        lr[m] += __shfl_xor(lr[m], 16);
        lr[m] += __shfl_xor(lr[m], 32);
    }
    __syncthreads();

    float* oK   = (float*)sK;
    float* oVf  = (float*)sV;
    float* obuf = qh ? oVf : oK;
    float* lbuf = oVf + 64 * 72;

    if (kvh == 1) {
#pragma unroll
        for (int m = 0; m < 4; ++m)
#pragma unroll
            for (int v = 0; v < 4; ++v)
                *(f32x4*)&obuf[(m * 16 + l15) * 72 + v * 16 + g * 4] = o[v][m];
        if (lane < 16) {
#pragma unroll
            for (int m = 0; m < 4; ++m)
                lbuf[qh * 64 + m * 16 + l15] = lr[m];
        }
    }
    __syncthreads();

    if (kvh == 0) {
        const int b = bh / 12, h = bh % 12;
#pragma unroll
        for (int m = 0; m < 4; ++m) {
            float lt = lr[m] + lbuf[qh * 64 + m * 16 + l15];
            float rl = frcp(lt);
            int q = q0 + qh * 64 + m * 16 + l15;
            unsigned short* dst = AO + (size_t)(b * 1024 + q) * 768 + h * 64 + g * 4;
#pragma unroll
            for (int v = 0; v < 4; ++v) {
                f32x4 add = *(const f32x4*)&obuf[(m * 16 + l15) * 72 + v * 16 + g * 4];
                uint2 w;
                w.x = pk2((o[v][m][0] + add[0]) * rl, (o[v][m][1] + add[1]) * rl);
                w.y = pk2((o[v][m][2] + add[2]) * rl, (o[v][m][3] + add[3]) * rl);
                *(uint2*)(dst + v * 16) = w;
            }
        }
    }
#undef STAGE_TILE
}

// ---------------------------------------------------------------------------
extern "C" void kernel_launch(void* const* d_in, const int* in_sizes, int n_in,
                              void* d_out, int out_size, void* d_ws, size_t ws_size,
                              hipStream_t stream)
{
    const float* x1 = (const float*)d_in[0];
    const float* x2 = (const float*)d_in[1];
    const float* Wq = (const float*)d_in[2];
    const float* Wk = (const float*)d_in[3];
    const float* Wv = (const float*)d_in[4];
    const float* Wo = (const float*)d_in[5];
    const float* bo = (const float*)d_in[6];

    unsigned short* Wcat = (unsigned short*)d_ws;        // 2304x768
    unsigned short* Wob  = Wcat + 1769472;               // 768x768
    unsigned short* x1b  = Wob  + 589824;                // 8192x768
    unsigned short* x2b  = x1b  + 6291456;               // 8192x768
    unsigned short* Qb   = x2b  + 6291456;               // (B,H,1024,64)
    unsigned short* Kc   = Qb   + 6291456;               // (B,H,2048,64)
    unsigned short* Vt   = Kc   + 12582912;              // (B,H,64,2048)
    unsigned short* AO   = x1b;                          // alias (x1b dead)

    convert_all<<<dim3(14592), 256, 0, stream>>>(x1, x2, Wq, Wk, Wv, Wo,
                                                 x1b, x2b, Wcat, Wob);

    gemm256<<<dim3(32, 15), 512, 0, stream>>>(x1b, x2b, Wcat, Qb, Kc, Vt);

    attn_k<<<dim3(96, 8), 256, 0, stream>>>(Qb, Kc, Vt, AO);

    gemm_out<<<dim3(64, 6), 256, 0, stream>>>(AO, Wob, (float*)d_out, bo);
}